// Round 7
// baseline (433.422 us; speedup 1.0000x reference)
//
#include <hip/hip_runtime.h>
#include <math.h>

#define HID 128
#define HEADS 8

typedef __attribute__((ext_vector_type(8))) short s16x8;
typedef __attribute__((ext_vector_type(4))) float f32x4;

__device__ __forceinline__ unsigned short bf16_rne(float x) {
  unsigned u = __float_as_uint(x);
  unsigned r = u + 0x7FFFu + ((u >> 16) & 1u);
  return (unsigned short)(r >> 16);
}
__device__ __forceinline__ float bf16f(unsigned short h) {
  return __uint_as_float(((unsigned)h) << 16);
}

// ================= dual-segment split-K GEMM (fp32) — input linears only =================
struct GSeg { const float* A; const float* B; int M; int K; int yb; };

__global__ __launch_bounds__(256, 3) void gemm2_splitk(
    GSeg s0, GSeg s1, float* __restrict__ P, int Mtot, int KS)
{
  __shared__ float As[16][132];
  __shared__ float Bs[16][132];
  const int tid = threadIdx.x;
  const float* A; const float* B; int M, K, rowbase, ytile;
  if ((int)blockIdx.x < s0.yb) {
    A = s0.A; B = s0.B; M = s0.M; K = s0.K; rowbase = 0; ytile = blockIdx.x;
  } else {
    A = s1.A; B = s1.B; M = s1.M; K = s1.K; rowbase = s0.yb * 128; ytile = blockIdx.x - s0.yb;
  }
  const int bm = ytile * 128;
  const int kchunk = K / KS;
  const int kbeg = blockIdx.y * kchunk;

  const int am = tid >> 1;
  const int ak = (tid & 1) << 3;
  const int brr = tid >> 4;
  const int bcc = (tid & 15) << 2;
  const int tx = tid & 15, ty = tid >> 4;

  float acc[64];
#pragma unroll
  for (int i = 0; i < 64; i++) acc[i] = 0.f;

  const int gr = bm + am;
  const float* Arow = A + (size_t)gr * K;
  for (int k0 = kbeg; k0 < kbeg + kchunk; k0 += 16) {
    float4 av0 = make_float4(0.f, 0.f, 0.f, 0.f), av1 = av0;
    if (gr < M) {
      av0 = *(const float4*)(Arow + k0 + ak);
      av1 = *(const float4*)(Arow + k0 + ak + 4);
    }
    const float4 bv0 = *(const float4*)(B + (size_t)(k0 + brr) * HID + bcc);
    const float4 bv1 = *(const float4*)(B + (size_t)(k0 + brr) * HID + bcc + 64);
    As[ak + 0][am] = av0.x; As[ak + 1][am] = av0.y;
    As[ak + 2][am] = av0.z; As[ak + 3][am] = av0.w;
    As[ak + 4][am] = av1.x; As[ak + 5][am] = av1.y;
    As[ak + 6][am] = av1.z; As[ak + 7][am] = av1.w;
    *(float4*)&Bs[brr][bcc] = bv0;
    *(float4*)&Bs[brr][bcc + 64] = bv1;
    __syncthreads();
#pragma unroll
    for (int kk = 0; kk < 16; kk++) {
      const float4 a0 = *(const float4*)&As[kk][ty << 3];
      const float4 a1 = *(const float4*)&As[kk][(ty << 3) + 4];
      const float4 b0 = *(const float4*)&Bs[kk][tx << 3];
      const float4 b1 = *(const float4*)&Bs[kk][(tx << 3) + 4];
      const float ar[8] = {a0.x, a0.y, a0.z, a0.w, a1.x, a1.y, a1.z, a1.w};
      const float bq[8] = {b0.x, b0.y, b0.z, b0.w, b1.x, b1.y, b1.z, b1.w};
#pragma unroll
      for (int i = 0; i < 8; i++)
#pragma unroll
        for (int j = 0; j < 8; j++) acc[i * 8 + j] = fmaf(ar[i], bq[j], acc[i * 8 + j]);
    }
    __syncthreads();
  }
  const size_t prow0 = (size_t)blockIdx.y * Mtot + rowbase + bm;
#pragma unroll
  for (int i = 0; i < 8; i++) {
    float* pp = P + (prow0 + (ty << 3) + i) * HID + (tx << 3);
    *(float4*)pp       = make_float4(acc[i * 8 + 0], acc[i * 8 + 1], acc[i * 8 + 2], acc[i * 8 + 3]);
    *(float4*)(pp + 4) = make_float4(acc[i * 8 + 4], acc[i * 8 + 5], acc[i * 8 + 6], acc[i * 8 + 7]);
  }
}

// ================= reduce KS partials + scale + bias + act =================
struct RSeg { float* out; const float* bias; int M; int rowbase; };

__global__ __launch_bounds__(256) void reduce_epi(
    const float* __restrict__ P, int Mtot, int KS, float scale, int do_relu,
    RSeg s0, RSeg s1)
{
  int idx = blockIdx.x * 256 + threadIdx.x;
  if (idx >= Mtot * 32) return;
  int r = idx >> 5;
  int c = (idx & 31) << 2;
  float* outp; const float* bias; int rl;
  if (s1.M > 0 && r >= s1.rowbase) {
    rl = r - s1.rowbase; if (rl >= s1.M) return; outp = s1.out; bias = s1.bias;
  } else {
    rl = r; if (rl >= s0.M) return; outp = s0.out; bias = s0.bias;
  }
  float4 acc = make_float4(0.f, 0.f, 0.f, 0.f);
  for (int z = 0; z < KS; z++) {
    const float4 v = *(const float4*)(P + ((size_t)z * Mtot + r) * HID + c);
    acc.x += v.x; acc.y += v.y; acc.z += v.z; acc.w += v.w;
  }
  const float4 b = *(const float4*)(bias + c);
  acc.x = acc.x * scale + b.x;
  acc.y = acc.y * scale + b.y;
  acc.z = acc.z * scale + b.z;
  acc.w = acc.w * scale + b.w;
  if (do_relu) {
    acc.x = acc.x > 0.f ? acc.x : 0.f;
    acc.y = acc.y > 0.f ? acc.y : 0.f;
    acc.z = acc.z > 0.f ? acc.z : 0.f;
    acc.w = acc.w > 0.f ? acc.w : 0.f;
  }
  *(float4*)(outp + (size_t)rl * HID + c) = acc;
}

// ================= upfront weight prep: 4x transposed bf16-split W + 8x make_v =============
struct PrepArgs {
  const float* W[8];
  const float* a[8];
  unsigned short* WThi[4];
  unsigned short* WTlo[4];
  float* v[8];
};

__global__ __launch_bounds__(256) void prep_weights(PrepArgs p)
{
  int bid = blockIdx.x;
  if (bid < 2048) {  // WT[g][c*1024 + (h*128+k)] = split(Ws[g][k*1024 + h*128 + c])
    int g = bid >> 9;
    int idx = ((bid & 511) << 8) + threadIdx.x;  // 0..131071  (= c*1024 + kidx)
    int kidx = idx & 1023;
    int c = idx >> 10;
    int h = kidx >> 7, k = kidx & 127;
    float wv = p.W[2 * g][(size_t)k * (HEADS * HID) + h * HID + c];
    unsigned short hi = bf16_rne(wv);
    unsigned short lo = bf16_rne(wv - bf16f(hi));
    p.WThi[g][idx] = hi;
    p.WTlo[g][idx] = lo;
  } else {           // v[wi][k*8+h] = sum_c W[wi][k, h*128+c] * a[wi][h,c]
    int u = bid - 2048;
    int wi = u >> 2;
    int gid = ((u & 3) << 8) + threadIdx.x;
    int k = gid >> 3, h = gid & 7;
    const float* wr = p.W[wi] + (size_t)k * (HEADS * HID) + h * HID;
    const float* ar = p.a[wi] + (size_t)h * HID;
    float s = 0.f;
    for (int c = 0; c < HID; c++) s = fmaf(wr[c], ar[c], s);
    p.v[wi][gid] = s;
  }
}

// ================= 4 attention-logit arrays per layer in one launch =================
__global__ __launch_bounds__(256) void compute_al4(
    const float* __restrict__ ha, const float* __restrict__ hb,
    const float* __restrict__ v4,
    float* __restrict__ o0, float* __restrict__ o1,
    float* __restrict__ o2, float* __restrict__ o3, int na, int nb)
{
  __shared__ float vsh[4 * HID * HEADS];
  for (int i = threadIdx.x; i < 4 * HID * HEADS; i += 256) vsh[i] = v4[i];
  __syncthreads();
  int gid = blockIdx.x * 256 + threadIdx.x;
  int row = gid >> 3, h = gid & 7;
  const float* hr; float* o; int q, rl;
  if (row < na)                    { q = 0; rl = row;               hr = ha; o = o0; }
  else if (row < na + nb)          { q = 1; rl = row - na;          hr = hb; o = o1; }
  else if (row < na + 2 * nb)      { q = 2; rl = row - na - nb;     hr = hb; o = o2; }
  else if (row < 2 * na + 2 * nb)  { q = 3; rl = row - na - 2 * nb; hr = ha; o = o3; }
  else return;
  hr += (size_t)rl * HID;
  const float* vq = vsh + q * HID * HEADS;
  float s = 0.f;
  for (int k = 0; k < HID; k++) s = fmaf(hr[k], vq[k * HEADS + h], s);
  o[(size_t)rl * HEADS + h] = s;
}

// ================= CSR build (both directions fused) =================
__global__ __launch_bounds__(256) void hist2(
    const int* __restrict__ dst_ab, const int* __restrict__ dst_ba,
    int* __restrict__ cnt_ab, int* __restrict__ cnt_ba, int E)
{
  int gid = blockIdx.x * 256 + threadIdx.x;
  if (gid < E) atomicAdd(&cnt_ab[dst_ab[gid]], 1);
  else if (gid < 2 * E) atomicAdd(&cnt_ba[dst_ba[gid - E]], 1);
}

__global__ __launch_bounds__(1024) void scan2(
    const int* __restrict__ cnt_ab, const int* __restrict__ cnt_ba,
    int* __restrict__ ip_ab, int* __restrict__ ip_ba, int n_ab, int n_ba)
{
  const int* cnt = (blockIdx.x == 0) ? cnt_ab : cnt_ba;
  int* indptr = (blockIdx.x == 0) ? ip_ab : ip_ba;
  int n = (blockIdx.x == 0) ? n_ab : n_ba;
  __shared__ int parts[1024];
  const int tid = threadIdx.x;
  const int base = tid * 10;
  int local[10];
  int s = 0;
#pragma unroll
  for (int j = 0; j < 10; j++) {
    int v = (base + j < n) ? cnt[base + j] : 0;
    local[j] = v; s += v;
  }
  parts[tid] = s;
  __syncthreads();
  for (int off = 1; off < 1024; off <<= 1) {
    int v = (tid >= off) ? parts[tid - off] : 0;
    __syncthreads();
    parts[tid] += v;
    __syncthreads();
  }
  int ex = parts[tid] - s;
#pragma unroll
  for (int j = 0; j < 10; j++) {
    if (base + j < n) indptr[base + j] = ex;
    ex += local[j];
  }
  if (tid == 1023) indptr[n] = parts[1023];
}

__global__ __launch_bounds__(256) void scatter2(
    const int* __restrict__ edge_ab, const int* __restrict__ edge_ba,
    const int* __restrict__ ip_ab, const int* __restrict__ ip_ba,
    int* __restrict__ cur_ab, int* __restrict__ cur_ba,
    int* __restrict__ srcs_ab, int* __restrict__ srcs_ba, int E)
{
  int gid = blockIdx.x * 256 + threadIdx.x;
  if (gid < E) {
    int d = edge_ab[E + gid];
    int pos = ip_ab[d] + atomicAdd(&cur_ab[d], 1);
    srcs_ab[pos] = edge_ab[gid];
  } else if (gid < 2 * E) {
    int g = gid - E;
    int d = edge_ba[E + g];
    int pos = ip_ba[d] + atomicAdd(&cur_ba[d], 1);
    srcs_ba[pos] = edge_ba[g];
  }
}

// ================= wave-per-node segment softmax + aggregation; writes bf16-split z =========
// Gather-early restructure (T14): h-row gathers depend only on srcs, NOT on exp/denom.
// Issue 16 gathers (chunks 0-1, covers deg<=16 ~90%) right after sc arrives; compute
// als-gather/exp/denom while they fly; FMA from landed regs. Chunks 2-3 serial (rare).
// NO min-wave launch bound (round-3 spill lesson). Target VGPR ~80-92 (<96).
struct GDir {
  const int* indptr; const int* srcs;
  const float* als; const float* ald;
  const float* h;
  unsigned short* zhi; unsigned short* zlo;
};

__global__ __launch_bounds__(256) void gat_edge2(GDir d0, GDir d1, int n0, int ntot)
{
  const int w = threadIdx.x >> 6;
  const int lane = threadIdx.x & 63;
  const int g = blockIdx.x * 4 + w;
  if (g >= ntot) return;
  const bool first = (g < n0);
  const int n = first ? g : g - n0;
  const int* indptr = first ? d0.indptr : d1.indptr;
  const int* srcs   = first ? d0.srcs   : d1.srcs;
  const float* als  = first ? d0.als    : d1.als;
  const float* ald  = first ? d0.ald    : d1.ald;
  const float* hsrc = first ? d0.h      : d1.h;
  unsigned short* zh = (first ? d0.zhi : d1.zhi) + (size_t)n * (HEADS * HID);
  unsigned short* zl = (first ? d0.zlo : d1.zlo) + (size_t)n * (HEADS * HID);

  const int base = indptr[n];
  const int deg = indptr[n + 1] - base;
  if (deg == 0) {
#pragma unroll
    for (int hh = 0; hh < HEADS; hh++) {
      *(unsigned*)(zh + hh * HID + 2 * lane) = 0u;
      *(unsigned*)(zl + hh * HID + 2 * lane) = 0u;
    }
    return;
  }
  const int eh = lane >> 3, h = lane & 7;
  const int nch = (deg + 7) >> 3;
  const int ncc = nch < 4 ? nch : 4;

  // srcs for cached region (deg<=32)
  int sc[4];
#pragma unroll
  for (int c = 0; c < 4; c++) {
    int e = c * 8 + eh;
    sc[c] = (c < ncc && e < deg) ? srcs[base + e] : -1;
  }

  // EARLY ISSUE: h-row gathers for chunks 0 and 1 (depend only on sc)
  float2 hv0[8], hv1[8];
  {
    int sj[8];
#pragma unroll
    for (int j = 0; j < 8; j++) {
      int s = __shfl(sc[0], j * 8);
      sj[j] = s < 0 ? 0 : s;
    }
#pragma unroll
    for (int j = 0; j < 8; j++)
      hv0[j] = *(const float2*)(hsrc + (size_t)sj[j] * HID + 2 * lane);
  }
  const bool two = (ncc > 1);
  if (two) {
    int sj[8];
#pragma unroll
    for (int j = 0; j < 8; j++) {
      int s = __shfl(sc[1], j * 8);
      sj[j] = s < 0 ? 0 : s;
    }
#pragma unroll
    for (int j = 0; j < 8; j++)
      hv1[j] = *(const float2*)(hsrc + (size_t)sj[j] * HID + 2 * lane);
  }

  // pass A (overlapped with the 16 in-flight gathers): als gather + exp + denom
  const float aldn = ald[(size_t)n * HEADS + h];
  float vc[4];
#pragma unroll
  for (int c = 0; c < 4; c++)
    vc[c] = (sc[c] >= 0) ? als[(size_t)sc[c] * HEADS + h] : 0.f;
  float den = 0.f;
#pragma unroll
  for (int c = 0; c < 4; c++) {
    float v = vc[c] + aldn;
    v = v > 0.f ? v : 0.2f * v;
    float ex = (sc[c] >= 0) ? expf(v) : 0.f;
    vc[c] = ex;
    den += ex;
  }
  for (int e0 = 32; e0 < deg; e0 += 8) {   // statistically-empty tail (deg>32)
    int e = e0 + eh;
    if (e < deg) {
      int s = srcs[base + e];
      float v = als[(size_t)s * HEADS + h] + aldn;
      v = v > 0.f ? v : 0.2f * v;
      den += expf(v);
    }
  }
  den += __shfl_xor(den, 8);
  den += __shfl_xor(den, 16);
  den += __shfl_xor(den, 32);

  // FMA chunks 0-1 from landed registers
  float acc[16];
#pragma unroll
  for (int i = 0; i < 16; i++) acc[i] = 0.f;
#pragma unroll
  for (int j = 0; j < 8; j++) {
#pragma unroll
    for (int hh = 0; hh < 8; hh++) {
      float a = __shfl(vc[0], j * 8 + hh);
      acc[2 * hh]     = fmaf(a, hv0[j].x, acc[2 * hh]);
      acc[2 * hh + 1] = fmaf(a, hv0[j].y, acc[2 * hh + 1]);
    }
  }
  if (two) {
#pragma unroll
    for (int j = 0; j < 8; j++) {
#pragma unroll
      for (int hh = 0; hh < 8; hh++) {
        float a = __shfl(vc[1], j * 8 + hh);
        acc[2 * hh]     = fmaf(a, hv1[j].x, acc[2 * hh]);
        acc[2 * hh + 1] = fmaf(a, hv1[j].y, acc[2 * hh + 1]);
      }
    }
  }
  // chunks 2-3 (deg>16, ~10% of nodes): gather -> FMA, statically unrolled
#pragma unroll
  for (int c = 2; c < 4; c++) {
    if (c >= ncc) break;
    int sj[8];
#pragma unroll
    for (int j = 0; j < 8; j++) {
      int s = __shfl(sc[c], j * 8);
      sj[j] = s < 0 ? 0 : s;
    }
#pragma unroll
    for (int j = 0; j < 8; j++)
      hv0[j] = *(const float2*)(hsrc + (size_t)sj[j] * HID + 2 * lane);
#pragma unroll
    for (int j = 0; j < 8; j++) {
#pragma unroll
      for (int hh = 0; hh < 8; hh++) {
        float a = __shfl(vc[c], j * 8 + hh);
        acc[2 * hh]     = fmaf(a, hv0[j].x, acc[2 * hh]);
        acc[2 * hh + 1] = fmaf(a, hv0[j].y, acc[2 * hh + 1]);
      }
    }
  }
  for (int e0 = 32; e0 < deg; e0 += 8) {   // statistically-empty tail: recompute exps
    int e = e0 + eh;
    int s = (e < deg) ? srcs[base + e] : -1;
    float ex = 0.f;
    if (s >= 0) {
      float v = als[(size_t)s * HEADS + h] + aldn;
      v = v > 0.f ? v : 0.2f * v;
      ex = expf(v);
    }
    int elim = deg - e0; if (elim > 8) elim = 8;
    for (int e8 = 0; e8 < elim; e8++) {
      int ss = __shfl(s, e8 * 8);
      const float2 hvt = *(const float2*)(hsrc + (size_t)ss * HID + 2 * lane);
#pragma unroll
      for (int hh = 0; hh < 8; hh++) {
        float a = __shfl(ex, e8 * 8 + hh);
        acc[2 * hh]     = fmaf(a, hvt.x, acc[2 * hh]);
        acc[2 * hh + 1] = fmaf(a, hvt.y, acc[2 * hh + 1]);
      }
    }
  }
  // epilogue: fold 1/(den+eps), write split-bf16 z
#pragma unroll
  for (int hh = 0; hh < 8; hh++) {
    float dh = __shfl(den, hh);
    float inv = 1.f / (dh + 1e-16f);
    float x0 = acc[2 * hh] * inv;
    float x1 = acc[2 * hh + 1] * inv;
    unsigned short h0 = bf16_rne(x0), h1 = bf16_rne(x1);
    unsigned short l0 = bf16_rne(x0 - bf16f(h0)), l1 = bf16_rne(x1 - bf16f(h1));
    *(unsigned*)(zh + hh * HID + 2 * lane) = (unsigned)h0 | ((unsigned)h1 << 16);
    *(unsigned*)(zl + hh * HID + 2 * lane) = (unsigned)l0 | ((unsigned)l1 << 16);
  }
}

// ================= MFMA bf16x4-split GEMM, SPLIT-K: [M x 1024] @ [1024 x 128] -> P =========
// BM=64, BN=128, BK=32; 4 waves; grid.y = KS K-slices (each 1024/KS of K).
// fp32 partials to P; reduce_epi applies 1/HEADS + bias + relu.
struct MSeg {
  const unsigned short* Ahi; const unsigned short* Alo;
  const unsigned short* Bhi; const unsigned short* Blo;
  int M; int yb;
};

__global__ __launch_bounds__(256, 2) void gemm_mfma_splitk(
    MSeg s0, MSeg s1, float* __restrict__ P, int Mtot, int KS)
{
  __shared__ __align__(16) unsigned short smem[12288];  // Ahi[64][32] Alo Bhi[128][32] Blo
  const int tid = threadIdx.x;
  const unsigned short *Ahi, *Alo, *Bhi, *Blo; int M, ytile, rowbase;
  if ((int)blockIdx.x < s0.yb) {
    Ahi = s0.Ahi; Alo = s0.Alo; Bhi = s0.Bhi; Blo = s0.Blo;
    M = s0.M; ytile = blockIdx.x; rowbase = 0;
  } else {
    Ahi = s1.Ahi; Alo = s1.Alo; Bhi = s1.Bhi; Blo = s1.Blo;
    M = s1.M; ytile = blockIdx.x - s0.yb; rowbase = s0.yb * 64;
  }
  const int bm = ytile * 64;
  const int kchunk = 1024 / KS;
  const int kbeg = blockIdx.y * kchunk;
  const int nks = kchunk / 32;

  // staging geometry: thread covers (row sr, src k-group sg); dest slot swizzled
  const int sr = tid >> 2;
  const int sg = tid & 3;
  const int g1 = sg ^ ((sr >> 1) & 3);
  const int sr2 = sr + 64;
  const int g2 = sg ^ ((sr2 >> 1) & 3);
  const int aslot  = sr * 32 + g1 * 8;
  const int bslotA = sr * 32 + g1 * 8;
  const int bslotB = sr2 * 32 + g2 * 8;
  const unsigned short* gA  = Ahi + (size_t)(bm + sr) * 1024 + kbeg + sg * 8;
  const unsigned short* gAl = Alo + (size_t)(bm + sr) * 1024 + kbeg + sg * 8;
  const unsigned short* gB0 = Bhi + (size_t)sr  * 1024 + kbeg + sg * 8;
  const unsigned short* gB1 = Bhi + (size_t)sr2 * 1024 + kbeg + sg * 8;
  const unsigned short* gC0 = Blo + (size_t)sr  * 1024 + kbeg + sg * 8;
  const unsigned short* gC1 = Blo + (size_t)sr2 * 1024 + kbeg + sg * 8;

  const int l = tid & 63;
  const int w = tid >> 6;
  const int kg = l >> 4;
  int aoff[4], boff[2];
#pragma unroll
  for (int mi = 0; mi < 4; mi++) {
    int r = mi * 16 + (l & 15);
    aoff[mi] = r * 32 + (kg ^ ((r >> 1) & 3)) * 8;
  }
#pragma unroll
  for (int ni = 0; ni < 2; ni++) {
    int r = w * 32 + ni * 16 + (l & 15);
    boff[ni] = r * 32 + (kg ^ ((r >> 1) & 3)) * 8;
  }

  f32x4 acc[4][2];
  const f32x4 z4 = {0.f, 0.f, 0.f, 0.f};
#pragma unroll
  for (int mi = 0; mi < 4; mi++)
#pragma unroll
    for (int ni = 0; ni < 2; ni++) acc[mi][ni] = z4;

  uint4 rA  = *(const uint4*)gA;
  uint4 rAl = *(const uint4*)gAl;
  uint4 rB0 = *(const uint4*)gB0;
  uint4 rB1 = *(const uint4*)gB1;
  uint4 rC0 = *(const uint4*)gC0;
  uint4 rC1 = *(const uint4*)gC1;

  for (int ks = 0; ks < nks; ks++) {
    *(uint4*)&smem[aslot]         = rA;
    *(uint4*)&smem[2048 + aslot]  = rAl;
    *(uint4*)&smem[4096 + bslotA] = rB0;
    *(uint4*)&smem[4096 + bslotB] = rB1;
    *(uint4*)&smem[8192 + bslotA] = rC0;
    *(uint4*)&smem[8192 + bslotB] = rC1;
    __syncthreads();
    if (ks < nks - 1) {  // prefetch next tile into regs; overlaps with MFMAs below
      const int k0 = (ks + 1) * 32;
      rA  = *(const uint4*)(gA  + k0);
      rAl = *(const uint4*)(gAl + k0);
      rB0 = *(const uint4*)(gB0 + k0);
      rB1 = *(const uint4*)(gB1 + k0);
      rC0 = *(const uint4*)(gC0 + k0);
      rC1 = *(const uint4*)(gC1 + k0);
    }
    s16x8 bh0 = *(const s16x8*)&smem[4096 + boff[0]];
    s16x8 bh1 = *(const s16x8*)&smem[4096 + boff[1]];
    s16x8 bl0 = *(const s16x8*)&smem[8192 + boff[0]];
    s16x8 bl1 = *(const s16x8*)&smem[8192 + boff[1]];
#pragma unroll
    for (int mi = 0; mi < 4; mi++) {
      s16x8 ah = *(const s16x8*)&smem[aoff[mi]];
      s16x8 al = *(const s16x8*)&smem[2048 + aoff[mi]];
      acc[mi][0] = __builtin_amdgcn_mfma_f32_16x16x32_bf16(ah, bh0, acc[mi][0], 0, 0, 0);
      acc[mi][1] = __builtin_amdgcn_mfma_f32_16x16x32_bf16(ah, bh1, acc[mi][1], 0, 0, 0);
      acc[mi][0] = __builtin_amdgcn_mfma_f32_16x16x32_bf16(ah, bl0, acc[mi][0], 0, 0, 0);
      acc[mi][1] = __builtin_amdgcn_mfma_f32_16x16x32_bf16(ah, bl1, acc[mi][1], 0, 0, 0);
      acc[mi][0] = __builtin_amdgcn_mfma_f32_16x16x32_bf16(al, bh0, acc[mi][0], 0, 0, 0);
      acc[mi][1] = __builtin_amdgcn_mfma_f32_16x16x32_bf16(al, bh1, acc[mi][1], 0, 0, 0);
      acc[mi][0] = __builtin_amdgcn_mfma_f32_16x16x32_bf16(al, bl0, acc[mi][0], 0, 0, 0);
      acc[mi][1] = __builtin_amdgcn_mfma_f32_16x16x32_bf16(al, bl1, acc[mi][1], 0, 0, 0);
    }
    __syncthreads();
  }

  // write fp32 partials to P slice (C/D: col=l&15, row=(l>>4)*4+j)
  const int q = l >> 4, cl = l & 15;
  const size_t prow0 = (size_t)blockIdx.y * Mtot + rowbase + bm;
#pragma unroll
  for (int ni = 0; ni < 2; ni++) {
    const int col = w * 32 + ni * 16 + cl;
#pragma unroll
    for (int mi = 0; mi < 4; mi++) {
      const int r0 = mi * 16 + q * 4;
      const f32x4 v = acc[mi][ni];
#pragma unroll
      for (int j = 0; j < 4; j++) {
        const int r = r0 + j;
        if (bm + r < M) P[(prow0 + r) * HID + col] = v[j];
      }
    }
  }
}

// ================= pool + FC =================
__global__ __launch_bounds__(256) void pool_dot2(
    const float* __restrict__ ha, const float* __restrict__ hb,
    const int* __restrict__ batch_a, const int* __restrict__ batch_b,
    const float* __restrict__ fc_w, float* __restrict__ gsum, int na, int nb)
{
  const bool isA = blockIdx.x < 160;
  const float* h = isA ? ha : hb;
  const int* batch = isA ? batch_a : batch_b;
  const float* wseg = isA ? fc_w : fc_w + HID;
  float* gs = isA ? gsum : gsum + 8;
  const int n = isA ? na : nb;
  const int b = isA ? blockIdx.x : blockIdx.x - 160;

  __shared__ float sg[8];
  if (threadIdx.x < 8) sg[threadIdx.x] = 0.f;
  __syncthreads();
  const int lane = threadIdx.x & 63;
  const int wv = threadIdx.x >> 6;
  const int gw = b * 4 + wv;
  const int tw = 160 * 4;
  const float2 w2 = *(const float2*)(wseg + lane * 2);
  for (int r = gw; r < n; r += tw) {
    float2 hv = *(const float2*)(h + (size_t)r * HID + lane * 2);
    float s = hv.x * w2.x + hv.y * w2.y;
#pragma unroll
    for (int off = 32; off > 0; off >>= 1) s += __shfl_down(s, off, 64);
    if (lane == 0) atomicAdd(&sg[batch[r]], s);
  }
  __syncthreads();
  if (threadIdx.x < 8) atomicAdd(&gs[threadIdx.x], sg[threadIdx.x]);
}

__global__ __launch_bounds__(64) void finalize_out(
    const float* __restrict__ gsum, const int* __restrict__ batch_a,
    const int* __restrict__ batch_b, const float* __restrict__ fc_b,
    float* __restrict__ out, int na, int nb, int ng)
{
  int g = threadIdx.x;
  if (g >= ng) return;
  int l, r, lo;
  l = 0; r = na; while (l < r) { int m = (l + r) >> 1; if (batch_a[m] < g) l = m + 1; else r = m; } lo = l;
  r = na; while (l < r) { int m = (l + r) >> 1; if (batch_a[m] < g + 1) l = m + 1; else r = m; }
  int ca = l - lo; if (ca < 1) ca = 1;
  l = 0; r = nb; while (l < r) { int m = (l + r) >> 1; if (batch_b[m] < g) l = m + 1; else r = m; } lo = l;
  r = nb; while (l < r) { int m = (l + r) >> 1; if (batch_b[m] < g + 1) l = m + 1; else r = m; }
  int cb = l - lo; if (cb < 1) cb = 1;
  out[g] = gsum[g] / (float)ca + gsum[8 + g] / (float)cb + fc_b[0];
}

extern "C" void kernel_launch(void* const* d_in, const int* in_sizes, int n_in,
                              void* d_out, int out_size, void* d_ws, size_t ws_size,
                              hipStream_t stream)
{
  const float* x_a = (const float*)d_in[0];
  const float* x_b = (const float*)d_in[1];
  const int* edge_ab = (const int*)d_in[2];
  const int* edge_ba = (const int*)d_in[3];
  const int* batch_a = (const int*)d_in[4];
  const int* batch_b = (const int*)d_in[5];
  const float* lin_a_w = (const float*)d_in[6];
  const float* lin_a_b = (const float*)d_in[7];
  const float* lin_b_w = (const float*)d_in[8];
  const float* lin_b_b = (const float*)d_in[9];
  const float* fc_w = (const float*)d_in[10];
  const float* fc_b = (const float*)d_in[11];

  const int NA = in_sizes[4];
  const int NB = in_sizes[5];
  const int E  = in_sizes[2] / 2;
  const int FA = in_sizes[0] / NA;
  const int FB = in_sizes[1] / NB;
  const int NG = out_size;
  const int NMAX = NA > NB ? NA : NB;
  const int NAp = (NA + 127) & ~127, NBp = (NB + 127) & ~127;
  const int NMAXp = NAp > NBp ? NAp : NBp;
  const int yba = NAp / 128, ybb = NBp / 128;
  const int Mtot = NAp + NBp;

  // ---- size model (mirrors carve order) ----
  auto al256 = [](size_t b) { return (b + 255) & ~(size_t)255; };
  size_t fixed = 0;
  fixed += 3 * al256((size_t)NAp * HID * 4) + 3 * al256((size_t)NBp * HID * 4);
  fixed += 2 * al256((size_t)NMAXp * 1024 * 2);                                   // z_ab hi+lo
  fixed += al256((size_t)8 * 131072 * 2);                                         // WT (4 mats x hi/lo)
  fixed += al256((size_t)8 * HID * HEADS * 4);                                    // vv
  fixed += 2 * al256((size_t)NAp * HEADS * 4) + 2 * al256((size_t)NBp * HEADS * 4);
  fixed += al256(((size_t)4 * NMAX + 16) * 4);
  fixed += al256((size_t)(NB + 1) * 4) + al256((size_t)(NA + 1) * 4);
  fixed += 2 * al256((size_t)E * 4);
  fixed += 8192;
  const size_t zba_sz = 2 * al256((size_t)NAp * 1024 * 2);
  const size_t pslice = al256((size_t)Mtot * HID * 4);

  int KS = 4; bool dual = true;
  if (fixed + zba_sz + 4 * pslice <= ws_size)      { dual = true;  KS = 4; }
  else if (fixed + zba_sz + 2 * pslice <= ws_size) { dual = true;  KS = 2; }
  else if (fixed + 4 * pslice <= ws_size)          { dual = false; KS = 4; }
  else if (fixed + 2 * pslice <= ws_size)          { dual = false; KS = 2; }
  else if (fixed + 1 * pslice <= ws_size)          { dual = false; KS = 1; }
  else return;  // loud failure (out stays poisoned)

  char* w = (char*)d_ws;
  auto carve = [&](size_t bytes) -> void* {
    void* p = (void*)w;
    w += (bytes + 255) & ~(size_t)255;
    return p;
  };
  float* ha0 = (float*)carve((size_t)NAp * HID * 4);
  float* hb0 = (float*)carve((size_t)NBp * HID * 4);
  float* ha1 = (float*)carve((size_t)NAp * HID * 4);
  float* hb1 = (float*)carve((size_t)NBp * HID * 4);
  float* ha2 = (float*)carve((size_t)NAp * HID * 4);
  float* hb2 = (float*)carve((size_t)NBp * HID * 4);
  unsigned short* zab_hi = (unsigned short*)carve((size_t)NMAXp * 1024 * 2);
  unsigned short* zab_lo = (unsigned short*)carve((size_t)NMAXp * 1024 * 2);
  unsigned short* zba_hi = dual ? (unsigned short*)carve((size_t)NAp * 1024 * 2) : zab_hi;
  unsigned short* zba_lo = dual ? (unsigned short*)carve((size_t)NAp * 1024 * 2) : zab_lo;
  float* P   = (float*)carve((size_t)KS * Mtot * HID * 4);
  unsigned short* WT = (unsigned short*)carve((size_t)8 * 131072 * 2);
  float* vv  = (float*)carve((size_t)8 * HID * HEADS * 4);
  float* als_ab = (float*)carve((size_t)NAp * HEADS * 4);
  float* ald_ab = (float*)carve((size_t)NBp * HEADS * 4);
  float* als_ba = (float*)carve((size_t)NBp * HEADS * 4);
  float* ald_ba = (float*)carve((size_t)NAp * HEADS * 4);
  int* csrblk = (int*)carve(((size_t)4 * NMAX + 16) * 4);
  int* indptr_ab = (int*)carve((size_t)(NB + 1) * 4);
  int* indptr_ba = (int*)carve((size_t)(NA + 1) * 4);
  int* srcs_ab   = (int*)carve((size_t)E * 4);
  int* srcs_ba   = (int*)carve((size_t)E * 4);
  if ((size_t)(w - (char*)d_ws) > ws_size) return;

  int* cnt_ab = csrblk;
  int* cnt_ba = csrblk + NMAX;
  int* cur_ab = csrblk + 2 * NMAX;
  int* cur_ba = csrblk + 3 * NMAX;
  float* gsum = (float*)(csrblk + 4 * NMAX);

  hipMemsetAsync(csrblk, 0, ((size_t)4 * NMAX + 16) * 4, stream);

  // ---- weight prep ----
  PrepArgs pa;
  const int wi_idx[8] = {12, 13, 17, 18, 22, 23, 27, 28};
  const int ai_idx[8] = {14, 15, 19, 20, 24, 25, 29, 30};
  for (int i = 0; i < 8; i++) {
    pa.W[i] = (const float*)d_in[wi_idx[i]];
    pa.a[i] = (const float*)d_in[ai_idx[i]];
    pa.v[i] = vv + (size_t)i * HID * HEADS;
  }
  for (int g = 0; g < 4; g++) {
    pa.WThi[g] = WT + (size_t)g * 131072;
    pa.WTlo[g] = WT + (size_t)(4 + g) * 131072;
  }
  prep_weights<<<2048 + 32, 256, 0, stream>>>(pa);

  // ---- CSR both directions ----
  hist2<<<(2 * E + 255) / 256, 256, 0, stream>>>(edge_ab + E, edge_ba + E, cnt_ab, cnt_ba, E);
  scan2<<<2, 1024, 0, stream>>>(cnt_ab, cnt_ba, indptr_ab, indptr_ba, NB, NA);
  scatter2<<<(2 * E + 255) / 256, 256, 0, stream>>>(
      edge_ab, edge_ba, indptr_ab, indptr_ba, cur_ab, cur_ba, srcs_ab, srcs_ba, E);

  const int red_grid = (Mtot * 32 + 255) / 256;
  const RSeg rnone = {nullptr, nullptr, 0, 0};

  // ---- input linears: one dual-segment split-K launch (fp32) ----
  {
    GSeg sa = {x_a, lin_a_w, NA, FA, yba};
    GSeg sb = {x_b, lin_b_w, NB, FB, ybb};
    gemm2_splitk<<<dim3(yba + ybb, KS), 256, 0, stream>>>(sa, sb, P, Mtot, KS);
    RSeg ra = {ha0, lin_a_b, NA, 0};
    RSeg rb = {hb0, lin_b_b, NB, yba * 128};
    reduce_epi<<<red_grid, 256, 0, stream>>>(P, Mtot, KS, 1.f, 1, ra, rb);
  }

  // ---- two GAT layers: logits -> edge softmax+agg (split-bf16 z) -> split-K MFMA GEMM ----
  auto run_layer = [&](int L, const float* haP, const float* hbP,
                       float* haN, float* hbN, const float* b_ab, const float* b_ba,
                       int relu) {
    compute_al4<<<((2 * (NA + NB)) * HEADS + 255) / 256, 256, 0, stream>>>(
        haP, hbP, vv + (size_t)L * 4 * HID * HEADS,
        als_ab, ald_ab, als_ba, ald_ba, NA, NB);
    GDir dab = {indptr_ab, srcs_ab, als_ab, ald_ab, haP, zab_hi, zab_lo};
    GDir dba = {indptr_ba, srcs_ba, als_ba, ald_ba, hbP, zba_hi, zba_lo};
    const int gab = 2 * L, gba = 2 * L + 1;
    MSeg mab = {zab_hi, zab_lo, WT + (size_t)gab * 131072, WT + (size_t)(4 + gab) * 131072,
                NB, NBp / 64};
    MSeg mba = {zba_hi, zba_lo, WT + (size_t)gba * 131072, WT + (size_t)(4 + gba) * 131072,
                NA, NAp / 64};
    if (dual) {
      gat_edge2<<<(NB + NA + 3) / 4, 256, 0, stream>>>(dab, dba, NB, NB + NA);
      gemm_mfma_splitk<<<dim3(NBp / 64 + NAp / 64, KS), 256, 0, stream>>>(mab, mba, P, Mtot, KS);
      RSeg r0 = {hbN, b_ab, NB, 0};
      RSeg r1 = {haN, b_ba, NA, NBp};
      reduce_epi<<<red_grid, 256, 0, stream>>>(P, Mtot, KS, 1.f / HEADS, relu, r0, r1);
    } else {
      MSeg mz = {nullptr, nullptr, nullptr, nullptr, 0, 0};
      gat_edge2<<<(NB + 3) / 4, 256, 0, stream>>>(dab, dab, NB, NB);
      gemm_mfma_splitk<<<dim3(NBp / 64, KS), 256, 0, stream>>>(mab, mz, P, NBp, KS);
      RSeg r0 = {hbN, b_ab, NB, 0};
      reduce_epi<<<(NBp * 32 + 255) / 256, 256, 0, stream>>>(P, NBp, KS, 1.f / HEADS, relu, r0, rnone);
      gat_edge2<<<(NA + 3) / 4, 256, 0, stream>>>(dba, dba, NA, NA);
      gemm_mfma_splitk<<<dim3(NAp / 64, KS), 256, 0, stream>>>(mba, mz, P, NAp, KS);
      RSeg r1 = {haN, b_ba, NA, 0};
      reduce_epi<<<(NAp * 32 + 255) / 256, 256, 0, stream>>>(P, NAp, KS, 1.f / HEADS, relu, r1, rnone);
    }
  };

  run_layer(0, ha0, hb0, ha1, hb1, (const float*)d_in[16], (const float*)d_in[21], 1);
  run_layer(1, ha1, hb1, ha2, hb2, (const float*)d_in[26], (const float*)d_in[31], 0);

  // ---- pooled mean + FC ----
  pool_dot2<<<320, 256, 0, stream>>>(ha2, hb2, batch_a, batch_b, fc_w, gsum, NA, NB);
  finalize_out<<<1, 64, 0, stream>>>(gsum, batch_a, batch_b, fc_b,
                                     (float*)d_out, NA, NB, NG);
}

// Round 8
// 391.169 us; speedup vs baseline: 1.1080x; 1.1080x over previous
//
#include <hip/hip_runtime.h>
#include <math.h>

#define HID 128
#define HEADS 8

typedef __attribute__((ext_vector_type(8))) short s16x8;
typedef __attribute__((ext_vector_type(4))) float f32x4;

__device__ __forceinline__ unsigned short bf16_rne(float x) {
  unsigned u = __float_as_uint(x);
  unsigned r = u + 0x7FFFu + ((u >> 16) & 1u);
  return (unsigned short)(r >> 16);
}
__device__ __forceinline__ float bf16f(unsigned short h) {
  return __uint_as_float(((unsigned)h) << 16);
}

// ================= reduce KS partials + scale + bias + act (input linears) =================
struct RSeg { float* out; const float* bias; int M; int rowbase; };

__global__ __launch_bounds__(256) void reduce_epi(
    const float* __restrict__ P, int Mtot, int KS, float scale, int do_relu,
    RSeg s0, RSeg s1)
{
  int idx = blockIdx.x * 256 + threadIdx.x;
  if (idx >= Mtot * 32) return;
  int r = idx >> 5;
  int c = (idx & 31) << 2;
  float* outp; const float* bias; int rl;
  if (s1.M > 0 && r >= s1.rowbase) {
    rl = r - s1.rowbase; if (rl >= s1.M) return; outp = s1.out; bias = s1.bias;
  } else {
    rl = r; if (rl >= s0.M) return; outp = s0.out; bias = s0.bias;
  }
  float4 acc = make_float4(0.f, 0.f, 0.f, 0.f);
  for (int z = 0; z < KS; z++) {
    const float4 v = *(const float4*)(P + ((size_t)z * Mtot + r) * HID + c);
    acc.x += v.x; acc.y += v.y; acc.z += v.z; acc.w += v.w;
  }
  const float4 b = *(const float4*)(bias + c);
  acc.x = acc.x * scale + b.x;
  acc.y = acc.y * scale + b.y;
  acc.z = acc.z * scale + b.z;
  acc.w = acc.w * scale + b.w;
  if (do_relu) {
    acc.x = acc.x > 0.f ? acc.x : 0.f;
    acc.y = acc.y > 0.f ? acc.y : 0.f;
    acc.z = acc.z > 0.f ? acc.z : 0.f;
    acc.w = acc.w > 0.f ? acc.w : 0.f;
  }
  *(float4*)(outp + (size_t)rl * HID + c) = acc;
}

// ============ fused: weight prep (transposed bf16-split W + make_v) + degree histogram ======
struct PrepArgs {
  const float* W[8];
  const float* a[8];
  unsigned short* WThi[4];
  unsigned short* WTlo[4];
  float* v[8];
};

__global__ __launch_bounds__(256) void prep_hist(
    PrepArgs p, const int* __restrict__ dst_ab, const int* __restrict__ dst_ba,
    int* __restrict__ cnt_ab, int* __restrict__ cnt_ba, int E)
{
  int bid = blockIdx.x;
  if (bid < 2048) {  // WT[g][c*1024 + (h*128+k)] = split(Ws[g][k*1024 + h*128 + c])
    int g = bid >> 9;
    int idx = ((bid & 511) << 8) + threadIdx.x;
    int kidx = idx & 1023;
    int c = idx >> 10;
    int h = kidx >> 7, k = kidx & 127;
    float wv = p.W[2 * g][(size_t)k * (HEADS * HID) + h * HID + c];
    unsigned short hi = bf16_rne(wv);
    unsigned short lo = bf16_rne(wv - bf16f(hi));
    p.WThi[g][idx] = hi;
    p.WTlo[g][idx] = lo;
  } else if (bid < 2080) {  // v[wi][k*8+h] = sum_c W[wi][k, h*128+c] * a[wi][h,c]
    int u = bid - 2048;
    int wi = u >> 2;
    int gid = ((u & 3) << 8) + threadIdx.x;
    int k = gid >> 3, h = gid & 7;
    const float* wr = p.W[wi] + (size_t)k * (HEADS * HID) + h * HID;
    const float* ar = p.a[wi] + (size_t)h * HID;
    float s = 0.f;
    for (int c = 0; c < HID; c++) s = fmaf(wr[c], ar[c], s);
    p.v[wi][gid] = s;
  } else {                  // degree histogram, both directions
    int gid = (bid - 2080) * 256 + threadIdx.x;
    if (gid < E) atomicAdd(&cnt_ab[dst_ab[gid]], 1);
    else if (gid < 2 * E) atomicAdd(&cnt_ba[dst_ba[gid - E]], 1);
  }
}

__global__ __launch_bounds__(1024) void scan2(
    const int* __restrict__ cnt_ab, const int* __restrict__ cnt_ba,
    int* __restrict__ ip_ab, int* __restrict__ ip_ba, int n_ab, int n_ba)
{
  const int* cnt = (blockIdx.x == 0) ? cnt_ab : cnt_ba;
  int* indptr = (blockIdx.x == 0) ? ip_ab : ip_ba;
  int n = (blockIdx.x == 0) ? n_ab : n_ba;
  __shared__ int parts[1024];
  const int tid = threadIdx.x;
  const int base = tid * 10;
  int local[10];
  int s = 0;
#pragma unroll
  for (int j = 0; j < 10; j++) {
    int v = (base + j < n) ? cnt[base + j] : 0;
    local[j] = v; s += v;
  }
  parts[tid] = s;
  __syncthreads();
  for (int off = 1; off < 1024; off <<= 1) {
    int v = (tid >= off) ? parts[tid - off] : 0;
    __syncthreads();
    parts[tid] += v;
    __syncthreads();
  }
  int ex = parts[tid] - s;
#pragma unroll
  for (int j = 0; j < 10; j++) {
    if (base + j < n) indptr[base + j] = ex;
    ex += local[j];
  }
  if (tid == 1023) indptr[n] = parts[1023];
}

// ======== fused: CSR scatter + dual-segment split-K fp32 GEMM (input linears) ==============
struct GSeg { const float* A; const float* B; int M; int K; int yb; };

__global__ __launch_bounds__(256, 3) void scatter_gemm_in(
    const int* __restrict__ edge_ab, const int* __restrict__ edge_ba,
    const int* __restrict__ ip_ab, const int* __restrict__ ip_ba,
    int* __restrict__ cur_ab, int* __restrict__ cur_ba,
    int* __restrict__ srcs_ab, int* __restrict__ srcs_ba, int E, int scat_b,
    GSeg s0, GSeg s1, float* __restrict__ P, int Mtot, int KS)
{
  __shared__ float As[16][132];
  __shared__ float Bs[16][132];
  const int bid0 = blockIdx.x;
  if (bid0 < scat_b) {  // scatter part (independent of GEMM part)
    int gid = bid0 * 256 + threadIdx.x;
    if (gid < E) {
      int d = edge_ab[E + gid];
      int pos = ip_ab[d] + atomicAdd(&cur_ab[d], 1);
      srcs_ab[pos] = edge_ab[gid];
    } else if (gid < 2 * E) {
      int g = gid - E;
      int d = edge_ba[E + g];
      int pos = ip_ba[d] + atomicAdd(&cur_ba[d], 1);
      srcs_ba[pos] = edge_ba[g];
    }
    return;
  }
  const int gg = bid0 - scat_b;
  const int nxt = s0.yb + s1.yb;
  const int bx = gg % nxt;
  const int by = gg / nxt;

  const int tid = threadIdx.x;
  const float* A; const float* B; int M, K, rowbase, ytile;
  if (bx < s0.yb) {
    A = s0.A; B = s0.B; M = s0.M; K = s0.K; rowbase = 0; ytile = bx;
  } else {
    A = s1.A; B = s1.B; M = s1.M; K = s1.K; rowbase = s0.yb * 128; ytile = bx - s0.yb;
  }
  const int bm = ytile * 128;
  const int kchunk = K / KS;
  const int kbeg = by * kchunk;

  const int am = tid >> 1;
  const int ak = (tid & 1) << 3;
  const int brr = tid >> 4;
  const int bcc = (tid & 15) << 2;
  const int tx = tid & 15, ty = tid >> 4;

  float acc[64];
#pragma unroll
  for (int i = 0; i < 64; i++) acc[i] = 0.f;

  const int gr = bm + am;
  const float* Arow = A + (size_t)gr * K;
  for (int k0 = kbeg; k0 < kbeg + kchunk; k0 += 16) {
    float4 av0 = make_float4(0.f, 0.f, 0.f, 0.f), av1 = av0;
    if (gr < M) {
      av0 = *(const float4*)(Arow + k0 + ak);
      av1 = *(const float4*)(Arow + k0 + ak + 4);
    }
    const float4 bv0 = *(const float4*)(B + (size_t)(k0 + brr) * HID + bcc);
    const float4 bv1 = *(const float4*)(B + (size_t)(k0 + brr) * HID + bcc + 64);
    As[ak + 0][am] = av0.x; As[ak + 1][am] = av0.y;
    As[ak + 2][am] = av0.z; As[ak + 3][am] = av0.w;
    As[ak + 4][am] = av1.x; As[ak + 5][am] = av1.y;
    As[ak + 6][am] = av1.z; As[ak + 7][am] = av1.w;
    *(float4*)&Bs[brr][bcc] = bv0;
    *(float4*)&Bs[brr][bcc + 64] = bv1;
    __syncthreads();
#pragma unroll
    for (int kk = 0; kk < 16; kk++) {
      const float4 a0 = *(const float4*)&As[kk][ty << 3];
      const float4 a1 = *(const float4*)&As[kk][(ty << 3) + 4];
      const float4 b0 = *(const float4*)&Bs[kk][tx << 3];
      const float4 b1 = *(const float4*)&Bs[kk][(tx << 3) + 4];
      const float ar[8] = {a0.x, a0.y, a0.z, a0.w, a1.x, a1.y, a1.z, a1.w};
      const float bq[8] = {b0.x, b0.y, b0.z, b0.w, b1.x, b1.y, b1.z, b1.w};
#pragma unroll
      for (int i = 0; i < 8; i++)
#pragma unroll
        for (int j = 0; j < 8; j++) acc[i * 8 + j] = fmaf(ar[i], bq[j], acc[i * 8 + j]);
    }
    __syncthreads();
  }
  const size_t prow0 = (size_t)by * Mtot + rowbase + bm;
#pragma unroll
  for (int i = 0; i < 8; i++) {
    float* pp = P + (prow0 + (ty << 3) + i) * HID + (tx << 3);
    *(float4*)pp       = make_float4(acc[i * 8 + 0], acc[i * 8 + 1], acc[i * 8 + 2], acc[i * 8 + 3]);
    *(float4*)(pp + 4) = make_float4(acc[i * 8 + 4], acc[i * 8 + 5], acc[i * 8 + 6], acc[i * 8 + 7]);
  }
}

// ================= 4 attention-logit arrays per layer in one launch =================
__global__ __launch_bounds__(256) void compute_al4(
    const float* __restrict__ ha, const float* __restrict__ hb,
    const float* __restrict__ v4,
    float* __restrict__ o0, float* __restrict__ o1,
    float* __restrict__ o2, float* __restrict__ o3, int na, int nb)
{
  __shared__ float vsh[4 * HID * HEADS];
  for (int i = threadIdx.x; i < 4 * HID * HEADS; i += 256) vsh[i] = v4[i];
  __syncthreads();
  int gid = blockIdx.x * 256 + threadIdx.x;
  int row = gid >> 3, h = gid & 7;
  const float* hr; float* o; int q, rl;
  if (row < na)                    { q = 0; rl = row;               hr = ha; o = o0; }
  else if (row < na + nb)          { q = 1; rl = row - na;          hr = hb; o = o1; }
  else if (row < na + 2 * nb)      { q = 2; rl = row - na - nb;     hr = hb; o = o2; }
  else if (row < 2 * na + 2 * nb)  { q = 3; rl = row - na - 2 * nb; hr = ha; o = o3; }
  else return;
  hr += (size_t)rl * HID;
  const float* vq = vsh + q * HID * HEADS;
  float s = 0.f;
  for (int k = 0; k < HID; k++) s = fmaf(hr[k], vq[k * HEADS + h], s);
  o[(size_t)rl * HEADS + h] = s;
}

// ================= wave-per-node segment softmax + aggregation; writes bf16-split z =========
// ROUND-5 PROVEN CONFIG (60 VGPR, batch-4 gathers, merged logit+exp pass, no launch bound).
// Bracketed frontier: 40 VGPR serial=47us, 60 VGPR batch-4=43-47us (best),
// 96-100 VGPR batch-8/gather-early=61-64us (R2/R7), 36 VGPR forced-cap=spills (R3).
struct GDir {
  const int* indptr; const int* srcs;
  const float* als; const float* ald;
  const float* h;
  unsigned short* zhi; unsigned short* zlo;
};

__global__ __launch_bounds__(256) void gat_edge2(GDir d0, GDir d1, int n0, int ntot)
{
  const int w = threadIdx.x >> 6;
  const int lane = threadIdx.x & 63;
  const int g = blockIdx.x * 4 + w;
  if (g >= ntot) return;
  const bool first = (g < n0);
  const int n = first ? g : g - n0;
  const int* indptr = first ? d0.indptr : d1.indptr;
  const int* srcs   = first ? d0.srcs   : d1.srcs;
  const float* als  = first ? d0.als    : d1.als;
  const float* ald  = first ? d0.ald    : d1.ald;
  const float* hsrc = first ? d0.h      : d1.h;
  unsigned short* zh = (first ? d0.zhi : d1.zhi) + (size_t)n * (HEADS * HID);
  unsigned short* zl = (first ? d0.zlo : d1.zlo) + (size_t)n * (HEADS * HID);

  const int base = indptr[n];
  const int deg = indptr[n + 1] - base;
  if (deg == 0) {
#pragma unroll
    for (int hh = 0; hh < HEADS; hh++) {
      *(unsigned*)(zh + hh * HID + 2 * lane) = 0u;
      *(unsigned*)(zl + hh * HID + 2 * lane) = 0u;
    }
    return;
  }
  const int eh = lane >> 3, h = lane & 7;
  const float aldn = ald[(size_t)n * HEADS + h];
  const int nch = (deg + 7) >> 3;
  const int ncc = nch < 4 ? nch : 4;

  // pass A: batched srcs loads + als gathers, exp (no max shift), denom
  int sc[4];
  float vc[4];
#pragma unroll
  for (int c = 0; c < 4; c++) {
    int e = c * 8 + eh;
    sc[c] = (c < ncc && e < deg) ? srcs[base + e] : -1;
  }
#pragma unroll
  for (int c = 0; c < 4; c++)
    vc[c] = (sc[c] >= 0) ? als[(size_t)sc[c] * HEADS + h] : 0.f;
  float den = 0.f;
#pragma unroll
  for (int c = 0; c < 4; c++) {
    float v = vc[c] + aldn;
    v = v > 0.f ? v : 0.2f * v;
    float ex = (sc[c] >= 0) ? expf(v) : 0.f;
    vc[c] = ex;
    den += ex;
  }
  for (int e0 = 32; e0 < deg; e0 += 8) {   // statistically-empty tail (deg>32)
    int e = e0 + eh;
    if (e < deg) {
      int s = srcs[base + e];
      float v = als[(size_t)s * HEADS + h] + aldn;
      v = v > 0.f ? v : 0.2f * v;
      den += expf(v);
    }
  }
  den += __shfl_xor(den, 8);
  den += __shfl_xor(den, 16);
  den += __shfl_xor(den, 32);

  // pass B: per 8-edge chunk, two half-batches of 4 concurrent row gathers
  float acc[16];
#pragma unroll
  for (int i = 0; i < 16; i++) acc[i] = 0.f;
#pragma unroll
  for (int c = 0; c < 4; c++) {
    if (c >= ncc) break;
    const int rem = deg - c * 8;
    const int elim = rem < 8 ? rem : 8;
#pragma unroll
    for (int half = 0; half < 2; half++) {
      if (half * 4 >= elim) break;
      int sj[4];
#pragma unroll
      for (int j = 0; j < 4; j++) {
        int s = __shfl(sc[c], (half * 4 + j) * 8);
        sj[j] = s < 0 ? 0 : s;
      }
      float2 hv[4];
#pragma unroll
      for (int j = 0; j < 4; j++)
        hv[j] = *(const float2*)(hsrc + (size_t)sj[j] * HID + 2 * lane);
#pragma unroll
      for (int j = 0; j < 4; j++) {
#pragma unroll
        for (int hh = 0; hh < 8; hh++) {
          float a = __shfl(vc[c], (half * 4 + j) * 8 + hh);
          acc[2 * hh]     = fmaf(a, hv[j].x, acc[2 * hh]);
          acc[2 * hh + 1] = fmaf(a, hv[j].y, acc[2 * hh + 1]);
        }
      }
    }
  }
  for (int e0 = 32; e0 < deg; e0 += 8) {   // statistically-empty tail: recompute exps
    int e = e0 + eh;
    int s = (e < deg) ? srcs[base + e] : -1;
    float ex = 0.f;
    if (s >= 0) {
      float v = als[(size_t)s * HEADS + h] + aldn;
      v = v > 0.f ? v : 0.2f * v;
      ex = expf(v);
    }
    int elim = deg - e0; if (elim > 8) elim = 8;
    for (int e8 = 0; e8 < elim; e8++) {
      int ss = __shfl(s, e8 * 8);
      const float2 hvt = *(const float2*)(hsrc + (size_t)ss * HID + 2 * lane);
#pragma unroll
      for (int hh = 0; hh < 8; hh++) {
        float a = __shfl(ex, e8 * 8 + hh);
        acc[2 * hh]     = fmaf(a, hvt.x, acc[2 * hh]);
        acc[2 * hh + 1] = fmaf(a, hvt.y, acc[2 * hh + 1]);
      }
    }
  }
  // epilogue: fold 1/(den+eps), write split-bf16 z
#pragma unroll
  for (int hh = 0; hh < 8; hh++) {
    float dh = __shfl(den, hh);
    float inv = 1.f / (dh + 1e-16f);
    float x0 = acc[2 * hh] * inv;
    float x1 = acc[2 * hh + 1] * inv;
    unsigned short h0 = bf16_rne(x0), h1 = bf16_rne(x1);
    unsigned short l0 = bf16_rne(x0 - bf16f(h0)), l1 = bf16_rne(x1 - bf16f(h1));
    *(unsigned*)(zh + hh * HID + 2 * lane) = (unsigned)h0 | ((unsigned)h1 << 16);
    *(unsigned*)(zl + hh * HID + 2 * lane) = (unsigned)l0 | ((unsigned)l1 << 16);
  }
}

// ========== MFMA bf16x4-split GEMM, 8-wave in-block K-split, fused epilogue ================
// [M x 1024] @ [1024 x 128]. BM=64, BN=128. 512 threads = 2 half-groups x 4 waves.
// Half h computes K in [h*512, h*512+512) into its own 24KB LDS staging region (16 k-steps
// of BK=32); then half-1 dumps acc to LDS (32KB, reusing staging) and half-0 adds + applies
// scale/bias/relu + stores. vs round-5 fused gemm (43us, occupancy 10%, 1.2 blk/CU, 32-step
// serial chain): chain halved, waves/block doubled, no P round-trip, no reduce_epi dispatch.
struct MSeg {
  const unsigned short* Ahi; const unsigned short* Alo;
  const unsigned short* Bhi; const unsigned short* Blo;
  float* out; const float* bias; int M; int yb;
};

__global__ __launch_bounds__(512) void gemm_mfma8(MSeg s0, MSeg s1, float scale, int do_relu)
{
  __shared__ __align__(16) unsigned short smem[24576];  // 2 x {Ahi[64][32] Alo Bhi[128][32] Blo}
  const int tid = threadIdx.x;
  const unsigned short *Ahi, *Alo, *Bhi, *Blo; const float* bias; float* out; int M, ytile;
  if ((int)blockIdx.x < s0.yb) {
    Ahi = s0.Ahi; Alo = s0.Alo; Bhi = s0.Bhi; Blo = s0.Blo;
    out = s0.out; bias = s0.bias; M = s0.M; ytile = blockIdx.x;
  } else {
    Ahi = s1.Ahi; Alo = s1.Alo; Bhi = s1.Bhi; Blo = s1.Blo;
    out = s1.out; bias = s1.bias; M = s1.M; ytile = blockIdx.x - s0.yb;
  }
  const int bm = ytile * 64;
  const int half = tid >> 8;       // 0 or 1
  const int t = tid & 255;
  const int kbase = half * 512;    // this half's K range start
  unsigned short* sm = smem + half * 12288;

  // staging geometry: thread covers (row sr, src k-group sg); dest slot swizzled
  const int sr = t >> 2;
  const int sg = t & 3;
  const int g1 = sg ^ ((sr >> 1) & 3);
  const int sr2 = sr + 64;
  const int g2 = sg ^ ((sr2 >> 1) & 3);
  const int aslot  = sr * 32 + g1 * 8;
  const int bslotA = sr * 32 + g1 * 8;
  const int bslotB = sr2 * 32 + g2 * 8;
  const unsigned short* gA  = Ahi + (size_t)(bm + sr) * 1024 + kbase + sg * 8;
  const unsigned short* gAl = Alo + (size_t)(bm + sr) * 1024 + kbase + sg * 8;
  const unsigned short* gB0 = Bhi + (size_t)sr  * 1024 + kbase + sg * 8;
  const unsigned short* gB1 = Bhi + (size_t)sr2 * 1024 + kbase + sg * 8;
  const unsigned short* gC0 = Blo + (size_t)sr  * 1024 + kbase + sg * 8;
  const unsigned short* gC1 = Blo + (size_t)sr2 * 1024 + kbase + sg * 8;

  const int l = t & 63;
  const int w = t >> 6;
  const int kg = l >> 4;
  int aoff[4], boff[2];
#pragma unroll
  for (int mi = 0; mi < 4; mi++) {
    int r = mi * 16 + (l & 15);
    aoff[mi] = r * 32 + (kg ^ ((r >> 1) & 3)) * 8;
  }
#pragma unroll
  for (int ni = 0; ni < 2; ni++) {
    int r = w * 32 + ni * 16 + (l & 15);
    boff[ni] = r * 32 + (kg ^ ((r >> 1) & 3)) * 8;
  }

  f32x4 acc[4][2];
  const f32x4 z4 = {0.f, 0.f, 0.f, 0.f};
#pragma unroll
  for (int mi = 0; mi < 4; mi++)
#pragma unroll
    for (int ni = 0; ni < 2; ni++) acc[mi][ni] = z4;

  uint4 rA  = *(const uint4*)gA;
  uint4 rAl = *(const uint4*)gAl;
  uint4 rB0 = *(const uint4*)gB0;
  uint4 rB1 = *(const uint4*)gB1;
  uint4 rC0 = *(const uint4*)gC0;
  uint4 rC1 = *(const uint4*)gC1;

  for (int ks = 0; ks < 16; ks++) {
    *(uint4*)&sm[aslot]         = rA;
    *(uint4*)&sm[2048 + aslot]  = rAl;
    *(uint4*)&sm[4096 + bslotA] = rB0;
    *(uint4*)&sm[4096 + bslotB] = rB1;
    *(uint4*)&sm[8192 + bslotA] = rC0;
    *(uint4*)&sm[8192 + bslotB] = rC1;
    __syncthreads();
    if (ks < 15) {  // prefetch next tile into regs; overlaps with MFMAs below
      const int k0 = (ks + 1) * 32;
      rA  = *(const uint4*)(gA  + k0);
      rAl = *(const uint4*)(gAl + k0);
      rB0 = *(const uint4*)(gB0 + k0);
      rB1 = *(const uint4*)(gB1 + k0);
      rC0 = *(const uint4*)(gC0 + k0);
      rC1 = *(const uint4*)(gC1 + k0);
    }
    s16x8 bh0 = *(const s16x8*)&sm[4096 + boff[0]];
    s16x8 bh1 = *(const s16x8*)&sm[4096 + boff[1]];
    s16x8 bl0 = *(const s16x8*)&sm[8192 + boff[0]];
    s16x8 bl1 = *(const s16x8*)&sm[8192 + boff[1]];
#pragma unroll
    for (int mi = 0; mi < 4; mi++) {
      s16x8 ah = *(const s16x8*)&sm[aoff[mi]];
      s16x8 al = *(const s16x8*)&sm[2048 + aoff[mi]];
      acc[mi][0] = __builtin_amdgcn_mfma_f32_16x16x32_bf16(ah, bh0, acc[mi][0], 0, 0, 0);
      acc[mi][1] = __builtin_amdgcn_mfma_f32_16x16x32_bf16(ah, bh1, acc[mi][1], 0, 0, 0);
      acc[mi][0] = __builtin_amdgcn_mfma_f32_16x16x32_bf16(ah, bl0, acc[mi][0], 0, 0, 0);
      acc[mi][1] = __builtin_amdgcn_mfma_f32_16x16x32_bf16(ah, bl1, acc[mi][1], 0, 0, 0);
      acc[mi][0] = __builtin_amdgcn_mfma_f32_16x16x32_bf16(al, bh0, acc[mi][0], 0, 0, 0);
      acc[mi][1] = __builtin_amdgcn_mfma_f32_16x16x32_bf16(al, bh1, acc[mi][1], 0, 0, 0);
      acc[mi][0] = __builtin_amdgcn_mfma_f32_16x16x32_bf16(al, bl0, acc[mi][0], 0, 0, 0);
      acc[mi][1] = __builtin_amdgcn_mfma_f32_16x16x32_bf16(al, bl1, acc[mi][1], 0, 0, 0);
    }
    __syncthreads();
  }

  // cross-half reduce in LDS (reuse staging; 64x128 fp32 = 32KB), then fused epilogue.
  float* fred = (float*)smem;
  const int q = l >> 4, cl = l & 15;
  if (half == 1) {
#pragma unroll
    for (int ni = 0; ni < 2; ni++) {
      const int col = w * 32 + ni * 16 + cl;
#pragma unroll
      for (int mi = 0; mi < 4; mi++) {
        const f32x4 v = acc[mi][ni];
#pragma unroll
        for (int j = 0; j < 4; j++)
          fred[(mi * 16 + q * 4 + j) * 128 + col] = v[j];
      }
    }
  }
  __syncthreads();
  if (half == 0) {
#pragma unroll
    for (int ni = 0; ni < 2; ni++) {
      const int col = w * 32 + ni * 16 + cl;
      const float bv = bias[col];
#pragma unroll
      for (int mi = 0; mi < 4; mi++) {
        const int rt = mi * 16 + q * 4;
        const f32x4 v = acc[mi][ni];
#pragma unroll
        for (int j = 0; j < 4; j++) {
          const int r = bm + rt + j;
          if (r < M) {
            float x = (v[j] + fred[(rt + j) * 128 + col]) * scale + bv;
            if (do_relu) x = fmaxf(x, 0.f);
            out[(size_t)r * HID + col] = x;
          }
        }
      }
    }
  }
}

// ================= fused pool + FC (atomic-ticket last-block finalize) =================
__global__ __launch_bounds__(256) void pool_fin(
    const float* __restrict__ ha, const float* __restrict__ hb,
    const int* __restrict__ batch_a, const int* __restrict__ batch_b,
    const float* __restrict__ fc_w, const float* __restrict__ fc_b,
    float* __restrict__ gsum, int* __restrict__ ticket,
    float* __restrict__ out, int na, int nb, int ng)
{
  const bool isA = blockIdx.x < 160;
  const float* h = isA ? ha : hb;
  const int* batch = isA ? batch_a : batch_b;
  const float* wseg = isA ? fc_w : fc_w + HID;
  float* gs = isA ? gsum : gsum + 8;
  const int n = isA ? na : nb;
  const int b = isA ? blockIdx.x : blockIdx.x - 160;

  __shared__ float sg[8];
  __shared__ int lastf;
  if (threadIdx.x < 8) sg[threadIdx.x] = 0.f;
  __syncthreads();
  const int lane = threadIdx.x & 63;
  const int wv = threadIdx.x >> 6;
  const int gw = b * 4 + wv;
  const int tw = 160 * 4;
  const float2 w2 = *(const float2*)(wseg + lane * 2);
  for (int r = gw; r < n; r += tw) {
    float2 hv = *(const float2*)(h + (size_t)r * HID + lane * 2);
    float s = hv.x * w2.x + hv.y * w2.y;
#pragma unroll
    for (int off = 32; off > 0; off >>= 1) s += __shfl_down(s, off, 64);
    if (lane == 0) atomicAdd(&sg[batch[r]], s);
  }
  __syncthreads();
  if (threadIdx.x < 8) atomicAdd(&gs[threadIdx.x], sg[threadIdx.x]);
  // ticket: last block to finish does the finalize
  if (threadIdx.x == 0) {
    __threadfence();
    int tk = atomicAdd(ticket, 1);
    lastf = (tk == (int)gridDim.x - 1);
  }
  __syncthreads();
  if (lastf) {
    int g = threadIdx.x;
    if (g < ng) {
      int l, r, lo;
      l = 0; r = na; while (l < r) { int m = (l + r) >> 1; if (batch_a[m] < g) l = m + 1; else r = m; } lo = l;
      r = na; while (l < r) { int m = (l + r) >> 1; if (batch_a[m] < g + 1) l = m + 1; else r = m; }
      int ca = l - lo; if (ca < 1) ca = 1;
      l = 0; r = nb; while (l < r) { int m = (l + r) >> 1; if (batch_b[m] < g) l = m + 1; else r = m; } lo = l;
      r = nb; while (l < r) { int m = (l + r) >> 1; if (batch_b[m] < g + 1) l = m + 1; else r = m; }
      int cb = l - lo; if (cb < 1) cb = 1;
      // coherent reads of other blocks' atomics (cross-XCD): atomic RMW with 0
      float va = atomicAdd(&gsum[g], 0.f);
      float vb = atomicAdd(&gsum[8 + g], 0.f);
      out[g] = va / (float)ca + vb / (float)cb + fc_b[0];
    }
  }
}

extern "C" void kernel_launch(void* const* d_in, const int* in_sizes, int n_in,
                              void* d_out, int out_size, void* d_ws, size_t ws_size,
                              hipStream_t stream)
{
  const float* x_a = (const float*)d_in[0];
  const float* x_b = (const float*)d_in[1];
  const int* edge_ab = (const int*)d_in[2];
  const int* edge_ba = (const int*)d_in[3];
  const int* batch_a = (const int*)d_in[4];
  const int* batch_b = (const int*)d_in[5];
  const float* lin_a_w = (const float*)d_in[6];
  const float* lin_a_b = (const float*)d_in[7];
  const float* lin_b_w = (const float*)d_in[8];
  const float* lin_b_b = (const float*)d_in[9];
  const float* fc_w = (const float*)d_in[10];
  const float* fc_b = (const float*)d_in[11];

  const int NA = in_sizes[4];
  const int NB = in_sizes[5];
  const int E  = in_sizes[2] / 2;
  const int FA = in_sizes[0] / NA;
  const int FB = in_sizes[1] / NB;
  const int NG = out_size;
  const int NMAX = NA > NB ? NA : NB;
  const int NAp = (NA + 127) & ~127, NBp = (NB + 127) & ~127;
  const int NMAXp = NAp > NBp ? NAp : NBp;
  const int yba = NAp / 128, ybb = NBp / 128;
  const int Mtot = NAp + NBp;

  // ---- size model (mirrors carve order) ----
  auto al256 = [](size_t b) { return (b + 255) & ~(size_t)255; };
  size_t fixed = 0;
  fixed += 3 * al256((size_t)NAp * HID * 4) + 3 * al256((size_t)NBp * HID * 4);
  fixed += 2 * al256((size_t)NMAXp * 1024 * 2);                                   // z_ab hi+lo
  fixed += al256((size_t)8 * 131072 * 2);                                         // WT (4 mats x hi/lo)
  fixed += al256((size_t)8 * HID * HEADS * 4);                                    // vv
  fixed += 2 * al256((size_t)NAp * HEADS * 4) + 2 * al256((size_t)NBp * HEADS * 4);
  fixed += al256(((size_t)4 * NMAX + 24) * 4);
  fixed += al256((size_t)(NB + 1) * 4) + al256((size_t)(NA + 1) * 4);
  fixed += 2 * al256((size_t)E * 4);
  fixed += 8192;
  const size_t zba_sz = 2 * al256((size_t)NAp * 1024 * 2);
  const size_t pslice = al256((size_t)Mtot * HID * 4);

  int KS = 4; bool dual = true;
  if (fixed + zba_sz + 4 * pslice <= ws_size)      { dual = true;  KS = 4; }
  else if (fixed + zba_sz + 2 * pslice <= ws_size) { dual = true;  KS = 2; }
  else if (fixed + 4 * pslice <= ws_size)          { dual = false; KS = 4; }
  else if (fixed + 2 * pslice <= ws_size)          { dual = false; KS = 2; }
  else if (fixed + 1 * pslice <= ws_size)          { dual = false; KS = 1; }
  else return;  // loud failure (out stays poisoned)

  char* w = (char*)d_ws;
  auto carve = [&](size_t bytes) -> void* {
    void* p = (void*)w;
    w += (bytes + 255) & ~(size_t)255;
    return p;
  };
  float* ha0 = (float*)carve((size_t)NAp * HID * 4);
  float* hb0 = (float*)carve((size_t)NBp * HID * 4);
  float* ha1 = (float*)carve((size_t)NAp * HID * 4);
  float* hb1 = (float*)carve((size_t)NBp * HID * 4);
  float* ha2 = (float*)carve((size_t)NAp * HID * 4);
  float* hb2 = (float*)carve((size_t)NBp * HID * 4);
  unsigned short* zab_hi = (unsigned short*)carve((size_t)NMAXp * 1024 * 2);
  unsigned short* zab_lo = (unsigned short*)carve((size_t)NMAXp * 1024 * 2);
  unsigned short* zba_hi = dual ? (unsigned short*)carve((size_t)NAp * 1024 * 2) : zab_hi;
  unsigned short* zba_lo = dual ? (unsigned short*)carve((size_t)NAp * 1024 * 2) : zab_lo;
  float* P   = (float*)carve((size_t)KS * Mtot * HID * 4);
  unsigned short* WT = (unsigned short*)carve((size_t)8 * 131072 * 2);
  float* vv  = (float*)carve((size_t)8 * HID * HEADS * 4);
  float* als_ab = (float*)carve((size_t)NAp * HEADS * 4);
  float* ald_ab = (float*)carve((size_t)NBp * HEADS * 4);
  float* als_ba = (float*)carve((size_t)NBp * HEADS * 4);
  float* ald_ba = (float*)carve((size_t)NAp * HEADS * 4);
  int* csrblk = (int*)carve(((size_t)4 * NMAX + 24) * 4);
  int* indptr_ab = (int*)carve((size_t)(NB + 1) * 4);
  int* indptr_ba = (int*)carve((size_t)(NA + 1) * 4);
  int* srcs_ab   = (int*)carve((size_t)E * 4);
  int* srcs_ba   = (int*)carve((size_t)E * 4);
  if ((size_t)(w - (char*)d_ws) > ws_size) return;

  int* cnt_ab = csrblk;
  int* cnt_ba = csrblk + NMAX;
  int* cur_ab = csrblk + 2 * NMAX;
  int* cur_ba = csrblk + 3 * NMAX;
  float* gsum = (float*)(csrblk + 4 * NMAX);
  int* ticket = csrblk + 4 * NMAX + 16;

  hipMemsetAsync(csrblk, 0, ((size_t)4 * NMAX + 24) * 4, stream);

  // ---- fused weight prep + histogram ----
  PrepArgs pa;
  const int wi_idx[8] = {12, 13, 17, 18, 22, 23, 27, 28};
  const int ai_idx[8] = {14, 15, 19, 20, 24, 25, 29, 30};
  for (int i = 0; i < 8; i++) {
    pa.W[i] = (const float*)d_in[wi_idx[i]];
    pa.a[i] = (const float*)d_in[ai_idx[i]];
    pa.v[i] = vv + (size_t)i * HID * HEADS;
  }
  for (int g = 0; g < 4; g++) {
    pa.WThi[g] = WT + (size_t)g * 131072;
    pa.WTlo[g] = WT + (size_t)(4 + g) * 131072;
  }
  const int hist_b = (2 * E + 255) / 256;
  prep_hist<<<2080 + hist_b, 256, 0, stream>>>(pa, edge_ab + E, edge_ba + E,
                                               cnt_ab, cnt_ba, E);
  scan2<<<2, 1024, 0, stream>>>(cnt_ab, cnt_ba, indptr_ab, indptr_ba, NB, NA);

  // ---- fused CSR scatter + input linears (independent work, one launch) ----
  {
    GSeg sa = {x_a, lin_a_w, NA, FA, yba};
    GSeg sb = {x_b, lin_b_w, NB, FB, ybb};
    const int scat_b = (2 * E + 255) / 256;
    scatter_gemm_in<<<scat_b + (yba + ybb) * KS, 256, 0, stream>>>(
        edge_ab, edge_ba, indptr_ab, indptr_ba, cur_ab, cur_ba,
        srcs_ab, srcs_ba, E, scat_b, sa, sb, P, Mtot, KS);
    RSeg ra = {ha0, lin_a_b, NA, 0};
    RSeg rb = {hb0, lin_b_b, NB, yba * 128};
    reduce_epi<<<(Mtot * 32 + 255) / 256, 256, 0, stream>>>(P, Mtot, KS, 1.f, 1, ra, rb);
  }

  // ---- two GAT layers: logits -> edge softmax+agg (split-bf16 z) -> 8-wave MFMA GEMM ----
  auto run_layer = [&](int L, const float* haP, const float* hbP,
                       float* haN, float* hbN, const float* b_ab, const float* b_ba,
                       int relu) {
    compute_al4<<<((2 * (NA + NB)) * HEADS + 255) / 256, 256, 0, stream>>>(
        haP, hbP, vv + (size_t)L * 4 * HID * HEADS,
        als_ab, ald_ab, als_ba, ald_ba, NA, NB);
    GDir dab = {indptr_ab, srcs_ab, als_ab, ald_ab, haP, zab_hi, zab_lo};
    GDir dba = {indptr_ba, srcs_ba, als_ba, ald_ba, hbP, zba_hi, zba_lo};
    const int gab = 2 * L, gba = 2 * L + 1;
    MSeg mab = {zab_hi, zab_lo, WT + (size_t)gab * 131072, WT + (size_t)(4 + gab) * 131072,
                hbN, b_ab, NB, NBp / 64};
    MSeg mba = {zba_hi, zba_lo, WT + (size_t)gba * 131072, WT + (size_t)(4 + gba) * 131072,
                haN, b_ba, NA, NAp / 64};
    if (dual) {
      gat_edge2<<<(NB + NA + 3) / 4, 256, 0, stream>>>(dab, dba, NB, NB + NA);
      gemm_mfma8<<<NBp / 64 + NAp / 64, 512, 0, stream>>>(mab, mba, 1.f / HEADS, relu);
    } else {
      MSeg mz = {nullptr, nullptr, nullptr, nullptr, nullptr, nullptr, 0, 0};
      gat_edge2<<<(NB + 3) / 4, 256, 0, stream>>>(dab, dab, NB, NB);
      gemm_mfma8<<<NBp / 64, 512, 0, stream>>>(mab, mz, 1.f / HEADS, relu);
      gat_edge2<<<(NA + 3) / 4, 256, 0, stream>>>(dba, dba, NA, NA);
      gemm_mfma8<<<NAp / 64, 512, 0, stream>>>(mba, mz, 1.f / HEADS, relu);
    }
  };

  run_layer(0, ha0, hb0, ha1, hb1, (const float*)d_in[16], (const float*)d_in[21], 1);
  run_layer(1, ha1, hb1, ha2, hb2, (const float*)d_in[26], (const float*)d_in[31], 0);

  // ---- fused pooled mean + FC ----
  pool_fin<<<320, 256, 0, stream>>>(ha2, hb2, batch_a, batch_b, fc_w, fc_b,
                                    gsum, ticket, (float*)d_out, NA, NB, NG);
}

// Round 9
// 371.899 us; speedup vs baseline: 1.1654x; 1.0518x over previous
//
#include <hip/hip_runtime.h>
#include <math.h>

#define HID 128
#define HEADS 8

typedef __attribute__((ext_vector_type(8))) short s16x8;
typedef __attribute__((ext_vector_type(4))) float f32x4;

__device__ __forceinline__ unsigned short bf16_rne(float x) {
  unsigned u = __float_as_uint(x);
  unsigned r = u + 0x7FFFu + ((u >> 16) & 1u);
  return (unsigned short)(r >> 16);
}
__device__ __forceinline__ float bf16f(unsigned short h) {
  return __uint_as_float(((unsigned)h) << 16);
}

// ====== fused prep: transposed bf16-split layer-W + make_v + input-W split + histogram ======
struct PrepArgs {
  const float* W[8];
  const float* a[8];
  unsigned short* WThi[4];
  unsigned short* WTlo[4];
  float* v[8];
};
struct PrepX {
  const float* lwa; const float* lwb;
  unsigned short *wa_hi, *wa_lo, *wb_hi, *wb_lo;
  int KA, KB, nwa, nwb;
};

__global__ __launch_bounds__(256) void prep_hist(
    PrepArgs p, PrepX px,
    const int* __restrict__ dst_ab, const int* __restrict__ dst_ba,
    int* __restrict__ cnt_ab, int* __restrict__ cnt_ba, int E)
{
  int bid = blockIdx.x;
  if (bid < 2048) {  // WT[g][c*1024 + (h*128+k)] = split(Ws[g][k*1024 + h*128 + c])
    int g = bid >> 9;
    int idx = ((bid & 511) << 8) + threadIdx.x;
    int kidx = idx & 1023;
    int c = idx >> 10;
    int h = kidx >> 7, k = kidx & 127;
    float wv = p.W[2 * g][(size_t)k * (HEADS * HID) + h * HID + c];
    unsigned short hi = bf16_rne(wv);
    unsigned short lo = bf16_rne(wv - bf16f(hi));
    p.WThi[g][idx] = hi;
    p.WTlo[g][idx] = lo;
  } else if (bid < 2080) {  // v[wi][k*8+h] = sum_c W[wi][k, h*128+c] * a[wi][h,c]
    int u = bid - 2048;
    int wi = u >> 2;
    int gid = ((u & 3) << 8) + threadIdx.x;
    int k = gid >> 3, h = gid & 7;
    const float* wr = p.W[wi] + (size_t)k * (HEADS * HID) + h * HID;
    const float* ar = p.a[wi] + (size_t)h * HID;
    float s = 0.f;
    for (int c = 0; c < HID; c++) s = fmaf(wr[c], ar[c], s);
    p.v[wi][gid] = s;
  } else if (bid < 2080 + px.nwa) {  // wa[c*KA + k] = split(lwa[k*HID + c])
    int idx = (bid - 2080) * 256 + threadIdx.x;
    if (idx < px.KA * HID) {
      int k = idx % px.KA, c = idx / px.KA;
      float wv = px.lwa[(size_t)k * HID + c];
      unsigned short hi = bf16_rne(wv);
      unsigned short lo = bf16_rne(wv - bf16f(hi));
      px.wa_hi[idx] = hi;
      px.wa_lo[idx] = lo;
    }
  } else if (bid < 2080 + px.nwa + px.nwb) {
    int idx = (bid - 2080 - px.nwa) * 256 + threadIdx.x;
    if (idx < px.KB * HID) {
      int k = idx % px.KB, c = idx / px.KB;
      float wv = px.lwb[(size_t)k * HID + c];
      unsigned short hi = bf16_rne(wv);
      unsigned short lo = bf16_rne(wv - bf16f(hi));
      px.wb_hi[idx] = hi;
      px.wb_lo[idx] = lo;
    }
  } else {                  // degree histogram, both directions
    int gid = (bid - 2080 - px.nwa - px.nwb) * 256 + threadIdx.x;
    if (gid < E) atomicAdd(&cnt_ab[dst_ab[gid]], 1);
    else if (gid < 2 * E) atomicAdd(&cnt_ba[dst_ba[gid - E]], 1);
  }
}

__global__ __launch_bounds__(1024) void scan2(
    const int* __restrict__ cnt_ab, const int* __restrict__ cnt_ba,
    int* __restrict__ ip_ab, int* __restrict__ ip_ba, int n_ab, int n_ba)
{
  const int* cnt = (blockIdx.x == 0) ? cnt_ab : cnt_ba;
  int* indptr = (blockIdx.x == 0) ? ip_ab : ip_ba;
  int n = (blockIdx.x == 0) ? n_ab : n_ba;
  __shared__ int parts[1024];
  const int tid = threadIdx.x;
  const int base = tid * 10;
  int local[10];
  int s = 0;
#pragma unroll
  for (int j = 0; j < 10; j++) {
    int v = (base + j < n) ? cnt[base + j] : 0;
    local[j] = v; s += v;
  }
  parts[tid] = s;
  __syncthreads();
  for (int off = 1; off < 1024; off <<= 1) {
    int v = (tid >= off) ? parts[tid - off] : 0;
    __syncthreads();
    parts[tid] += v;
    __syncthreads();
  }
  int ex = parts[tid] - s;
#pragma unroll
  for (int j = 0; j < 10; j++) {
    if (base + j < n) indptr[base + j] = ex;
    ex += local[j];
  }
  if (tid == 1023) indptr[n] = parts[1023];
}

__global__ __launch_bounds__(256) void scatter2(
    const int* __restrict__ edge_ab, const int* __restrict__ edge_ba,
    const int* __restrict__ ip_ab, const int* __restrict__ ip_ba,
    int* __restrict__ cur_ab, int* __restrict__ cur_ba,
    int* __restrict__ srcs_ab, int* __restrict__ srcs_ba, int E)
{
  int gid = blockIdx.x * 256 + threadIdx.x;
  if (gid < E) {
    int d = edge_ab[E + gid];
    int pos = ip_ab[d] + atomicAdd(&cur_ab[d], 1);
    srcs_ab[pos] = edge_ab[gid];
  } else if (gid < 2 * E) {
    int g = gid - E;
    int d = edge_ba[E + g];
    int pos = ip_ba[d] + atomicAdd(&cur_ba[d], 1);
    srcs_ba[pos] = edge_ba[g];
  }
}

// ===== input linears: MFMA bf16-split GEMM, fp32 A split on the fly, fused bias+relu =======
// [M x K] @ [K x 128], K = 256 or 128 -> only 8 or 4 K-steps (short serial chain).
// B pre-split/transposed by prep_hist ([col][K] hi/lo). Replaces fp32 VALU GEMM + reduce_epi
// (R8: 42us + 9us, VALUBusy 14%) with ~1 GFLOP on the matrix pipe.
struct ISeg {
  const float* A;
  const unsigned short* Bhi; const unsigned short* Blo;
  float* out; const float* bias; int M; int K; int yb;
};

__global__ __launch_bounds__(256) void gemm_mfma_in(ISeg s0, ISeg s1)
{
  __shared__ __align__(16) unsigned short smem[12288];  // Ahi[64][32] Alo Bhi[128][32] Blo
  const int tid = threadIdx.x;
  const float* A; const unsigned short *Bhi, *Blo; const float* bias; float* out;
  int M, K, ytile;
  if ((int)blockIdx.x < s0.yb) {
    A = s0.A; Bhi = s0.Bhi; Blo = s0.Blo; out = s0.out; bias = s0.bias;
    M = s0.M; K = s0.K; ytile = blockIdx.x;
  } else {
    A = s1.A; Bhi = s1.Bhi; Blo = s1.Blo; out = s1.out; bias = s1.bias;
    M = s1.M; K = s1.K; ytile = blockIdx.x - s0.yb;
  }
  const int bm = ytile * 64;
  const int nks = K >> 5;

  const int sr = tid >> 2;
  const int sg = tid & 3;
  const int g1 = sg ^ ((sr >> 1) & 3);
  const int sr2 = sr + 64;
  const int g2 = sg ^ ((sr2 >> 1) & 3);
  const int aslot  = sr * 32 + g1 * 8;
  const int bslotA = sr * 32 + g1 * 8;
  const int bslotB = sr2 * 32 + g2 * 8;
  const int gr = bm + sr;
  const bool arow_ok = (gr < M);
  const float* gA = A + (size_t)gr * K + sg * 8;
  const unsigned short* gB0 = Bhi + (size_t)sr  * K + sg * 8;
  const unsigned short* gB1 = Bhi + (size_t)sr2 * K + sg * 8;
  const unsigned short* gC0 = Blo + (size_t)sr  * K + sg * 8;
  const unsigned short* gC1 = Blo + (size_t)sr2 * K + sg * 8;

  const int l = tid & 63;
  const int w = tid >> 6;
  const int kg = l >> 4;
  int aoff[4], boff[2];
#pragma unroll
  for (int mi = 0; mi < 4; mi++) {
    int r = mi * 16 + (l & 15);
    aoff[mi] = r * 32 + (kg ^ ((r >> 1) & 3)) * 8;
  }
#pragma unroll
  for (int ni = 0; ni < 2; ni++) {
    int r = w * 32 + ni * 16 + (l & 15);
    boff[ni] = r * 32 + (kg ^ ((r >> 1) & 3)) * 8;
  }

  f32x4 acc[4][2];
  const f32x4 z4 = {0.f, 0.f, 0.f, 0.f};
#pragma unroll
  for (int mi = 0; mi < 4; mi++)
#pragma unroll
    for (int ni = 0; ni < 2; ni++) acc[mi][ni] = z4;

  float4 fa0 = make_float4(0.f, 0.f, 0.f, 0.f), fa1 = fa0;
  if (arow_ok) { fa0 = *(const float4*)gA; fa1 = *(const float4*)(gA + 4); }
  uint4 rB0 = *(const uint4*)gB0;
  uint4 rB1 = *(const uint4*)gB1;
  uint4 rC0 = *(const uint4*)gC0;
  uint4 rC1 = *(const uint4*)gC1;

  for (int ks = 0; ks < nks; ks++) {
    // split A regs to bf16 hi/lo and stage everything
    {
      const float f[8] = {fa0.x, fa0.y, fa0.z, fa0.w, fa1.x, fa1.y, fa1.z, fa1.w};
      unsigned au[4], lu[4];
#pragma unroll
      for (int i = 0; i < 4; i++) {
        unsigned short h0 = bf16_rne(f[2 * i]);
        unsigned short l0 = bf16_rne(f[2 * i] - bf16f(h0));
        unsigned short h1 = bf16_rne(f[2 * i + 1]);
        unsigned short l1 = bf16_rne(f[2 * i + 1] - bf16f(h1));
        au[i] = (unsigned)h0 | ((unsigned)h1 << 16);
        lu[i] = (unsigned)l0 | ((unsigned)l1 << 16);
      }
      *(uint4*)&smem[aslot]        = make_uint4(au[0], au[1], au[2], au[3]);
      *(uint4*)&smem[2048 + aslot] = make_uint4(lu[0], lu[1], lu[2], lu[3]);
    }
    *(uint4*)&smem[4096 + bslotA] = rB0;
    *(uint4*)&smem[4096 + bslotB] = rB1;
    *(uint4*)&smem[8192 + bslotA] = rC0;
    *(uint4*)&smem[8192 + bslotB] = rC1;
    __syncthreads();
    if (ks < nks - 1) {  // prefetch next tile; overlaps with MFMAs below
      const int k0 = (ks + 1) * 32;
      if (arow_ok) {
        fa0 = *(const float4*)(gA + k0);
        fa1 = *(const float4*)(gA + k0 + 4);
      }
      rB0 = *(const uint4*)(gB0 + k0);
      rB1 = *(const uint4*)(gB1 + k0);
      rC0 = *(const uint4*)(gC0 + k0);
      rC1 = *(const uint4*)(gC1 + k0);
    }
    s16x8 bh0 = *(const s16x8*)&smem[4096 + boff[0]];
    s16x8 bh1 = *(const s16x8*)&smem[4096 + boff[1]];
    s16x8 bl0 = *(const s16x8*)&smem[8192 + boff[0]];
    s16x8 bl1 = *(const s16x8*)&smem[8192 + boff[1]];
#pragma unroll
    for (int mi = 0; mi < 4; mi++) {
      s16x8 ah = *(const s16x8*)&smem[aoff[mi]];
      s16x8 al = *(const s16x8*)&smem[2048 + aoff[mi]];
      acc[mi][0] = __builtin_amdgcn_mfma_f32_16x16x32_bf16(ah, bh0, acc[mi][0], 0, 0, 0);
      acc[mi][1] = __builtin_amdgcn_mfma_f32_16x16x32_bf16(ah, bh1, acc[mi][1], 0, 0, 0);
      acc[mi][0] = __builtin_amdgcn_mfma_f32_16x16x32_bf16(ah, bl0, acc[mi][0], 0, 0, 0);
      acc[mi][1] = __builtin_amdgcn_mfma_f32_16x16x32_bf16(ah, bl1, acc[mi][1], 0, 0, 0);
      acc[mi][0] = __builtin_amdgcn_mfma_f32_16x16x32_bf16(al, bh0, acc[mi][0], 0, 0, 0);
      acc[mi][1] = __builtin_amdgcn_mfma_f32_16x16x32_bf16(al, bh1, acc[mi][1], 0, 0, 0);
      acc[mi][0] = __builtin_amdgcn_mfma_f32_16x16x32_bf16(al, bl0, acc[mi][0], 0, 0, 0);
      acc[mi][1] = __builtin_amdgcn_mfma_f32_16x16x32_bf16(al, bl1, acc[mi][1], 0, 0, 0);
    }
    __syncthreads();
  }

  // fused epilogue: bias + relu, direct store (C/D: col=l&15, row=(l>>4)*4+j)
  const int q = l >> 4, cl = l & 15;
#pragma unroll
  for (int ni = 0; ni < 2; ni++) {
    const int col = w * 32 + ni * 16 + cl;
    const float bv = bias[col];
#pragma unroll
    for (int mi = 0; mi < 4; mi++) {
      const int r0 = bm + mi * 16 + q * 4;
      const f32x4 v = acc[mi][ni];
#pragma unroll
      for (int j = 0; j < 4; j++) {
        const int r = r0 + j;
        if (r < M) {
          float x = v[j] + bv;
          x = fmaxf(x, 0.f);
          out[(size_t)r * HID + col] = x;
        }
      }
    }
  }
}

// ================= 4 attention-logit arrays per layer in one launch =================
__global__ __launch_bounds__(256) void compute_al4(
    const float* __restrict__ ha, const float* __restrict__ hb,
    const float* __restrict__ v4,
    float* __restrict__ o0, float* __restrict__ o1,
    float* __restrict__ o2, float* __restrict__ o3, int na, int nb)
{
  __shared__ float vsh[4 * HID * HEADS];
  for (int i = threadIdx.x; i < 4 * HID * HEADS; i += 256) vsh[i] = v4[i];
  __syncthreads();
  int gid = blockIdx.x * 256 + threadIdx.x;
  int row = gid >> 3, h = gid & 7;
  const float* hr; float* o; int q, rl;
  if (row < na)                    { q = 0; rl = row;               hr = ha; o = o0; }
  else if (row < na + nb)          { q = 1; rl = row - na;          hr = hb; o = o1; }
  else if (row < na + 2 * nb)      { q = 2; rl = row - na - nb;     hr = hb; o = o2; }
  else if (row < 2 * na + 2 * nb)  { q = 3; rl = row - na - 2 * nb; hr = ha; o = o3; }
  else return;
  hr += (size_t)rl * HID;
  const float* vq = vsh + q * HID * HEADS;
  float s = 0.f;
  for (int k = 0; k < HID; k++) s = fmaf(hr[k], vq[k * HEADS + h], s);
  o[(size_t)rl * HEADS + h] = s;
}

// ================= wave-per-node segment softmax + aggregation; writes bf16-split z =========
// ROUND-5 PROVEN CONFIG (60 VGPR, batch-4 gathers, merged logit+exp pass, no launch bound).
struct GDir {
  const int* indptr; const int* srcs;
  const float* als; const float* ald;
  const float* h;
  unsigned short* zhi; unsigned short* zlo;
};

__global__ __launch_bounds__(256) void gat_edge2(GDir d0, GDir d1, int n0, int ntot)
{
  const int w = threadIdx.x >> 6;
  const int lane = threadIdx.x & 63;
  const int g = blockIdx.x * 4 + w;
  if (g >= ntot) return;
  const bool first = (g < n0);
  const int n = first ? g : g - n0;
  const int* indptr = first ? d0.indptr : d1.indptr;
  const int* srcs   = first ? d0.srcs   : d1.srcs;
  const float* als  = first ? d0.als    : d1.als;
  const float* ald  = first ? d0.ald    : d1.ald;
  const float* hsrc = first ? d0.h      : d1.h;
  unsigned short* zh = (first ? d0.zhi : d1.zhi) + (size_t)n * (HEADS * HID);
  unsigned short* zl = (first ? d0.zlo : d1.zlo) + (size_t)n * (HEADS * HID);

  const int base = indptr[n];
  const int deg = indptr[n + 1] - base;
  if (deg == 0) {
#pragma unroll
    for (int hh = 0; hh < HEADS; hh++) {
      *(unsigned*)(zh + hh * HID + 2 * lane) = 0u;
      *(unsigned*)(zl + hh * HID + 2 * lane) = 0u;
    }
    return;
  }
  const int eh = lane >> 3, h = lane & 7;
  const float aldn = ald[(size_t)n * HEADS + h];
  const int nch = (deg + 7) >> 3;
  const int ncc = nch < 4 ? nch : 4;

  // pass A: batched srcs loads + als gathers, exp (no max shift), denom
  int sc[4];
  float vc[4];
#pragma unroll
  for (int c = 0; c < 4; c++) {
    int e = c * 8 + eh;
    sc[c] = (c < ncc && e < deg) ? srcs[base + e] : -1;
  }
#pragma unroll
  for (int c = 0; c < 4; c++)
    vc[c] = (sc[c] >= 0) ? als[(size_t)sc[c] * HEADS + h] : 0.f;
  float den = 0.f;
#pragma unroll
  for (int c = 0; c < 4; c++) {
    float v = vc[c] + aldn;
    v = v > 0.f ? v : 0.2f * v;
    float ex = (sc[c] >= 0) ? expf(v) : 0.f;
    vc[c] = ex;
    den += ex;
  }
  for (int e0 = 32; e0 < deg; e0 += 8) {   // statistically-empty tail (deg>32)
    int e = e0 + eh;
    if (e < deg) {
      int s = srcs[base + e];
      float v = als[(size_t)s * HEADS + h] + aldn;
      v = v > 0.f ? v : 0.2f * v;
      den += expf(v);
    }
  }
  den += __shfl_xor(den, 8);
  den += __shfl_xor(den, 16);
  den += __shfl_xor(den, 32);

  // pass B: per 8-edge chunk, two half-batches of 4 concurrent row gathers
  float acc[16];
#pragma unroll
  for (int i = 0; i < 16; i++) acc[i] = 0.f;
#pragma unroll
  for (int c = 0; c < 4; c++) {
    if (c >= ncc) break;
    const int rem = deg - c * 8;
    const int elim = rem < 8 ? rem : 8;
#pragma unroll
    for (int half = 0; half < 2; half++) {
      if (half * 4 >= elim) break;
      int sj[4];
#pragma unroll
      for (int j = 0; j < 4; j++) {
        int s = __shfl(sc[c], (half * 4 + j) * 8);
        sj[j] = s < 0 ? 0 : s;
      }
      float2 hv[4];
#pragma unroll
      for (int j = 0; j < 4; j++)
        hv[j] = *(const float2*)(hsrc + (size_t)sj[j] * HID + 2 * lane);
#pragma unroll
      for (int j = 0; j < 4; j++) {
#pragma unroll
        for (int hh = 0; hh < 8; hh++) {
          float a = __shfl(vc[c], (half * 4 + j) * 8 + hh);
          acc[2 * hh]     = fmaf(a, hv[j].x, acc[2 * hh]);
          acc[2 * hh + 1] = fmaf(a, hv[j].y, acc[2 * hh + 1]);
        }
      }
    }
  }
  for (int e0 = 32; e0 < deg; e0 += 8) {   // statistically-empty tail: recompute exps
    int e = e0 + eh;
    int s = (e < deg) ? srcs[base + e] : -1;
    float ex = 0.f;
    if (s >= 0) {
      float v = als[(size_t)s * HEADS + h] + aldn;
      v = v > 0.f ? v : 0.2f * v;
      ex = expf(v);
    }
    int elim = deg - e0; if (elim > 8) elim = 8;
    for (int e8 = 0; e8 < elim; e8++) {
      int ss = __shfl(s, e8 * 8);
      const float2 hvt = *(const float2*)(hsrc + (size_t)ss * HID + 2 * lane);
#pragma unroll
      for (int hh = 0; hh < 8; hh++) {
        float a = __shfl(ex, e8 * 8 + hh);
        acc[2 * hh]     = fmaf(a, hvt.x, acc[2 * hh]);
        acc[2 * hh + 1] = fmaf(a, hvt.y, acc[2 * hh + 1]);
      }
    }
  }
  // epilogue: fold 1/(den+eps), write split-bf16 z
#pragma unroll
  for (int hh = 0; hh < 8; hh++) {
    float dh = __shfl(den, hh);
    float inv = 1.f / (dh + 1e-16f);
    float x0 = acc[2 * hh] * inv;
    float x1 = acc[2 * hh + 1] * inv;
    unsigned short h0 = bf16_rne(x0), h1 = bf16_rne(x1);
    unsigned short l0 = bf16_rne(x0 - bf16f(h0)), l1 = bf16_rne(x1 - bf16f(h1));
    *(unsigned*)(zh + hh * HID + 2 * lane) = (unsigned)h0 | ((unsigned)h1 << 16);
    *(unsigned*)(zl + hh * HID + 2 * lane) = (unsigned)l0 | ((unsigned)l1 << 16);
  }
}

// ========== MFMA bf16x4-split GEMM, 8-wave in-block K-split, fused epilogue ================
struct MSeg {
  const unsigned short* Ahi; const unsigned short* Alo;
  const unsigned short* Bhi; const unsigned short* Blo;
  float* out; const float* bias; int M; int yb;
};

__global__ __launch_bounds__(512) void gemm_mfma8(MSeg s0, MSeg s1, float scale, int do_relu)
{
  __shared__ __align__(16) unsigned short smem[24576];  // 2 x {Ahi[64][32] Alo Bhi[128][32] Blo}
  const int tid = threadIdx.x;
  const unsigned short *Ahi, *Alo, *Bhi, *Blo; const float* bias; float* out; int M, ytile;
  if ((int)blockIdx.x < s0.yb) {
    Ahi = s0.Ahi; Alo = s0.Alo; Bhi = s0.Bhi; Blo = s0.Blo;
    out = s0.out; bias = s0.bias; M = s0.M; ytile = blockIdx.x;
  } else {
    Ahi = s1.Ahi; Alo = s1.Alo; Bhi = s1.Bhi; Blo = s1.Blo;
    out = s1.out; bias = s1.bias; M = s1.M; ytile = blockIdx.x - s0.yb;
  }
  const int bm = ytile * 64;
  const int half = tid >> 8;
  const int t = tid & 255;
  const int kbase = half * 512;
  unsigned short* sm = smem + half * 12288;

  const int sr = t >> 2;
  const int sg = t & 3;
  const int g1 = sg ^ ((sr >> 1) & 3);
  const int sr2 = sr + 64;
  const int g2 = sg ^ ((sr2 >> 1) & 3);
  const int aslot  = sr * 32 + g1 * 8;
  const int bslotA = sr * 32 + g1 * 8;
  const int bslotB = sr2 * 32 + g2 * 8;
  const unsigned short* gA  = Ahi + (size_t)(bm + sr) * 1024 + kbase + sg * 8;
  const unsigned short* gAl = Alo + (size_t)(bm + sr) * 1024 + kbase + sg * 8;
  const unsigned short* gB0 = Bhi + (size_t)sr  * 1024 + kbase + sg * 8;
  const unsigned short* gB1 = Bhi + (size_t)sr2 * 1024 + kbase + sg * 8;
  const unsigned short* gC0 = Blo + (size_t)sr  * 1024 + kbase + sg * 8;
  const unsigned short* gC1 = Blo + (size_t)sr2 * 1024 + kbase + sg * 8;

  const int l = t & 63;
  const int w = t >> 6;
  const int kg = l >> 4;
  int aoff[4], boff[2];
#pragma unroll
  for (int mi = 0; mi < 4; mi++) {
    int r = mi * 16 + (l & 15);
    aoff[mi] = r * 32 + (kg ^ ((r >> 1) & 3)) * 8;
  }
#pragma unroll
  for (int ni = 0; ni < 2; ni++) {
    int r = w * 32 + ni * 16 + (l & 15);
    boff[ni] = r * 32 + (kg ^ ((r >> 1) & 3)) * 8;
  }

  f32x4 acc[4][2];
  const f32x4 z4 = {0.f, 0.f, 0.f, 0.f};
#pragma unroll
  for (int mi = 0; mi < 4; mi++)
#pragma unroll
    for (int ni = 0; ni < 2; ni++) acc[mi][ni] = z4;

  uint4 rA  = *(const uint4*)gA;
  uint4 rAl = *(const uint4*)gAl;
  uint4 rB0 = *(const uint4*)gB0;
  uint4 rB1 = *(const uint4*)gB1;
  uint4 rC0 = *(const uint4*)gC0;
  uint4 rC1 = *(const uint4*)gC1;

  for (int ks = 0; ks < 16; ks++) {
    *(uint4*)&sm[aslot]         = rA;
    *(uint4*)&sm[2048 + aslot]  = rAl;
    *(uint4*)&sm[4096 + bslotA] = rB0;
    *(uint4*)&sm[4096 + bslotB] = rB1;
    *(uint4*)&sm[8192 + bslotA] = rC0;
    *(uint4*)&sm[8192 + bslotB] = rC1;
    __syncthreads();
    if (ks < 15) {
      const int k0 = (ks + 1) * 32;
      rA  = *(const uint4*)(gA  + k0);
      rAl = *(const uint4*)(gAl + k0);
      rB0 = *(const uint4*)(gB0 + k0);
      rB1 = *(const uint4*)(gB1 + k0);
      rC0 = *(const uint4*)(gC0 + k0);
      rC1 = *(const uint4*)(gC1 + k0);
    }
    s16x8 bh0 = *(const s16x8*)&sm[4096 + boff[0]];
    s16x8 bh1 = *(const s16x8*)&sm[4096 + boff[1]];
    s16x8 bl0 = *(const s16x8*)&sm[8192 + boff[0]];
    s16x8 bl1 = *(const s16x8*)&sm[8192 + boff[1]];
#pragma unroll
    for (int mi = 0; mi < 4; mi++) {
      s16x8 ah = *(const s16x8*)&sm[aoff[mi]];
      s16x8 al = *(const s16x8*)&sm[2048 + aoff[mi]];
      acc[mi][0] = __builtin_amdgcn_mfma_f32_16x16x32_bf16(ah, bh0, acc[mi][0], 0, 0, 0);
      acc[mi][1] = __builtin_amdgcn_mfma_f32_16x16x32_bf16(ah, bh1, acc[mi][1], 0, 0, 0);
      acc[mi][0] = __builtin_amdgcn_mfma_f32_16x16x32_bf16(ah, bl0, acc[mi][0], 0, 0, 0);
      acc[mi][1] = __builtin_amdgcn_mfma_f32_16x16x32_bf16(ah, bl1, acc[mi][1], 0, 0, 0);
      acc[mi][0] = __builtin_amdgcn_mfma_f32_16x16x32_bf16(al, bh0, acc[mi][0], 0, 0, 0);
      acc[mi][1] = __builtin_amdgcn_mfma_f32_16x16x32_bf16(al, bh1, acc[mi][1], 0, 0, 0);
      acc[mi][0] = __builtin_amdgcn_mfma_f32_16x16x32_bf16(al, bl0, acc[mi][0], 0, 0, 0);
      acc[mi][1] = __builtin_amdgcn_mfma_f32_16x16x32_bf16(al, bl1, acc[mi][1], 0, 0, 0);
    }
    __syncthreads();
  }

  // cross-half reduce in LDS (reuse staging; 64x128 fp32 = 32KB), then fused epilogue.
  float* fred = (float*)smem;
  const int q = l >> 4, cl = l & 15;
  if (half == 1) {
#pragma unroll
    for (int ni = 0; ni < 2; ni++) {
      const int col = w * 32 + ni * 16 + cl;
#pragma unroll
      for (int mi = 0; mi < 4; mi++) {
        const f32x4 v = acc[mi][ni];
#pragma unroll
        for (int j = 0; j < 4; j++)
          fred[(mi * 16 + q * 4 + j) * 128 + col] = v[j];
      }
    }
  }
  __syncthreads();
  if (half == 0) {
#pragma unroll
    for (int ni = 0; ni < 2; ni++) {
      const int col = w * 32 + ni * 16 + cl;
      const float bv = bias[col];
#pragma unroll
      for (int mi = 0; mi < 4; mi++) {
        const int rt = mi * 16 + q * 4;
        const f32x4 v = acc[mi][ni];
#pragma unroll
        for (int j = 0; j < 4; j++) {
          const int r = bm + rt + j;
          if (r < M) {
            float x = (v[j] + fred[(rt + j) * 128 + col]) * scale + bv;
            if (do_relu) x = fmaxf(x, 0.f);
            out[(size_t)r * HID + col] = x;
          }
        }
      }
    }
  }
}

// ================= fused pool + FC (atomic-ticket last-block finalize) =================
__global__ __launch_bounds__(256) void pool_fin(
    const float* __restrict__ ha, const float* __restrict__ hb,
    const int* __restrict__ batch_a, const int* __restrict__ batch_b,
    const float* __restrict__ fc_w, const float* __restrict__ fc_b,
    float* __restrict__ gsum, int* __restrict__ ticket,
    float* __restrict__ out, int na, int nb, int ng)
{
  const bool isA = blockIdx.x < 160;
  const float* h = isA ? ha : hb;
  const int* batch = isA ? batch_a : batch_b;
  const float* wseg = isA ? fc_w : fc_w + HID;
  float* gs = isA ? gsum : gsum + 8;
  const int n = isA ? na : nb;
  const int b = isA ? blockIdx.x : blockIdx.x - 160;

  __shared__ float sg[8];
  __shared__ int lastf;
  if (threadIdx.x < 8) sg[threadIdx.x] = 0.f;
  __syncthreads();
  const int lane = threadIdx.x & 63;
  const int wv = threadIdx.x >> 6;
  const int gw = b * 4 + wv;
  const int tw = 160 * 4;
  const float2 w2 = *(const float2*)(wseg + lane * 2);
  for (int r = gw; r < n; r += tw) {
    float2 hv = *(const float2*)(h + (size_t)r * HID + lane * 2);
    float s = hv.x * w2.x + hv.y * w2.y;
#pragma unroll
    for (int off = 32; off > 0; off >>= 1) s += __shfl_down(s, off, 64);
    if (lane == 0) atomicAdd(&sg[batch[r]], s);
  }
  __syncthreads();
  if (threadIdx.x < 8) atomicAdd(&gs[threadIdx.x], sg[threadIdx.x]);
  if (threadIdx.x == 0) {
    __threadfence();
    int tk = atomicAdd(ticket, 1);
    lastf = (tk == (int)gridDim.x - 1);
  }
  __syncthreads();
  if (lastf) {
    int g = threadIdx.x;
    if (g < ng) {
      int l, r, lo;
      l = 0; r = na; while (l < r) { int m = (l + r) >> 1; if (batch_a[m] < g) l = m + 1; else r = m; } lo = l;
      r = na; while (l < r) { int m = (l + r) >> 1; if (batch_a[m] < g + 1) l = m + 1; else r = m; }
      int ca = l - lo; if (ca < 1) ca = 1;
      l = 0; r = nb; while (l < r) { int m = (l + r) >> 1; if (batch_b[m] < g) l = m + 1; else r = m; } lo = l;
      r = nb; while (l < r) { int m = (l + r) >> 1; if (batch_b[m] < g + 1) l = m + 1; else r = m; }
      int cb = l - lo; if (cb < 1) cb = 1;
      float va = atomicAdd(&gsum[g], 0.f);
      float vb = atomicAdd(&gsum[8 + g], 0.f);
      out[g] = va / (float)ca + vb / (float)cb + fc_b[0];
    }
  }
}

extern "C" void kernel_launch(void* const* d_in, const int* in_sizes, int n_in,
                              void* d_out, int out_size, void* d_ws, size_t ws_size,
                              hipStream_t stream)
{
  const float* x_a = (const float*)d_in[0];
  const float* x_b = (const float*)d_in[1];
  const int* edge_ab = (const int*)d_in[2];
  const int* edge_ba = (const int*)d_in[3];
  const int* batch_a = (const int*)d_in[4];
  const int* batch_b = (const int*)d_in[5];
  const float* lin_a_w = (const float*)d_in[6];
  const float* lin_a_b = (const float*)d_in[7];
  const float* lin_b_w = (const float*)d_in[8];
  const float* lin_b_b = (const float*)d_in[9];
  const float* fc_w = (const float*)d_in[10];
  const float* fc_b = (const float*)d_in[11];

  const int NA = in_sizes[4];
  const int NB = in_sizes[5];
  const int E  = in_sizes[2] / 2;
  const int FA = in_sizes[0] / NA;
  const int FB = in_sizes[1] / NB;
  const int NG = out_size;
  const int NMAX = NA > NB ? NA : NB;
  const int NAp = (NA + 127) & ~127, NBp = (NB + 127) & ~127;
  const int NMAXp = NAp > NBp ? NAp : NBp;

  // ---- size model (mirrors carve order) ----
  auto al256 = [](size_t b) { return (b + 255) & ~(size_t)255; };
  size_t fixed = 0;
  fixed += 3 * al256((size_t)NAp * HID * 4) + 3 * al256((size_t)NBp * HID * 4);
  fixed += 2 * al256((size_t)NMAXp * 1024 * 2);                                   // z_ab hi+lo
  fixed += al256((size_t)8 * 131072 * 2);                                         // WT layer (4 x hi/lo)
  fixed += 2 * al256((size_t)FA * HID * 2) + 2 * al256((size_t)FB * HID * 2);     // WTin hi/lo
  fixed += al256((size_t)8 * HID * HEADS * 4);                                    // vv
  fixed += 2 * al256((size_t)NAp * HEADS * 4) + 2 * al256((size_t)NBp * HEADS * 4);
  fixed += al256(((size_t)4 * NMAX + 24) * 4);
  fixed += al256((size_t)(NB + 1) * 4) + al256((size_t)(NA + 1) * 4);
  fixed += 2 * al256((size_t)E * 4);
  fixed += 8192;
  const size_t zba_sz = 2 * al256((size_t)NAp * 1024 * 2);

  bool dual = (fixed + zba_sz <= ws_size);
  if (fixed > ws_size) return;  // loud failure (out stays poisoned)

  char* w = (char*)d_ws;
  auto carve = [&](size_t bytes) -> void* {
    void* p = (void*)w;
    w += (bytes + 255) & ~(size_t)255;
    return p;
  };
  float* ha0 = (float*)carve((size_t)NAp * HID * 4);
  float* hb0 = (float*)carve((size_t)NBp * HID * 4);
  float* ha1 = (float*)carve((size_t)NAp * HID * 4);
  float* hb1 = (float*)carve((size_t)NBp * HID * 4);
  float* ha2 = (float*)carve((size_t)NAp * HID * 4);
  float* hb2 = (float*)carve((size_t)NBp * HID * 4);
  unsigned short* zab_hi = (unsigned short*)carve((size_t)NMAXp * 1024 * 2);
  unsigned short* zab_lo = (unsigned short*)carve((size_t)NMAXp * 1024 * 2);
  unsigned short* zba_hi = dual ? (unsigned short*)carve((size_t)NAp * 1024 * 2) : zab_hi;
  unsigned short* zba_lo = dual ? (unsigned short*)carve((size_t)NAp * 1024 * 2) : zab_lo;
  unsigned short* WT = (unsigned short*)carve((size_t)8 * 131072 * 2);
  unsigned short* wa_hi = (unsigned short*)carve((size_t)FA * HID * 2);
  unsigned short* wa_lo = (unsigned short*)carve((size_t)FA * HID * 2);
  unsigned short* wb_hi = (unsigned short*)carve((size_t)FB * HID * 2);
  unsigned short* wb_lo = (unsigned short*)carve((size_t)FB * HID * 2);
  float* vv  = (float*)carve((size_t)8 * HID * HEADS * 4);
  float* als_ab = (float*)carve((size_t)NAp * HEADS * 4);
  float* ald_ab = (float*)carve((size_t)NBp * HEADS * 4);
  float* als_ba = (float*)carve((size_t)NBp * HEADS * 4);
  float* ald_ba = (float*)carve((size_t)NAp * HEADS * 4);
  int* csrblk = (int*)carve(((size_t)4 * NMAX + 24) * 4);
  int* indptr_ab = (int*)carve((size_t)(NB + 1) * 4);
  int* indptr_ba = (int*)carve((size_t)(NA + 1) * 4);
  int* srcs_ab   = (int*)carve((size_t)E * 4);
  int* srcs_ba   = (int*)carve((size_t)E * 4);
  if ((size_t)(w - (char*)d_ws) > ws_size) return;

  int* cnt_ab = csrblk;
  int* cnt_ba = csrblk + NMAX;
  int* cur_ab = csrblk + 2 * NMAX;
  int* cur_ba = csrblk + 3 * NMAX;
  float* gsum = (float*)(csrblk + 4 * NMAX);
  int* ticket = csrblk + 4 * NMAX + 16;

  hipMemsetAsync(csrblk, 0, ((size_t)4 * NMAX + 24) * 4, stream);

  // ---- fused weight prep (layer WT + v + input WT) + histogram ----
  PrepArgs pa;
  const int wi_idx[8] = {12, 13, 17, 18, 22, 23, 27, 28};
  const int ai_idx[8] = {14, 15, 19, 20, 24, 25, 29, 30};
  for (int i = 0; i < 8; i++) {
    pa.W[i] = (const float*)d_in[wi_idx[i]];
    pa.a[i] = (const float*)d_in[ai_idx[i]];
    pa.v[i] = vv + (size_t)i * HID * HEADS;
  }
  for (int g = 0; g < 4; g++) {
    pa.WThi[g] = WT + (size_t)g * 131072;
    pa.WTlo[g] = WT + (size_t)(4 + g) * 131072;
  }
  PrepX px;
  px.lwa = lin_a_w; px.lwb = lin_b_w;
  px.wa_hi = wa_hi; px.wa_lo = wa_lo; px.wb_hi = wb_hi; px.wb_lo = wb_lo;
  px.KA = FA; px.KB = FB;
  px.nwa = (FA * HID + 255) / 256;
  px.nwb = (FB * HID + 255) / 256;
  const int hist_b = (2 * E + 255) / 256;
  prep_hist<<<2080 + px.nwa + px.nwb + hist_b, 256, 0, stream>>>(
      pa, px, edge_ab + E, edge_ba + E, cnt_ab, cnt_ba, E);
  scan2<<<2, 1024, 0, stream>>>(cnt_ab, cnt_ba, indptr_ab, indptr_ba, NB, NA);
  scatter2<<<(2 * E + 255) / 256, 256, 0, stream>>>(
      edge_ab, edge_ba, indptr_ab, indptr_ba, cur_ab, cur_ba, srcs_ab, srcs_ba, E);

  // ---- input linears: MFMA split GEMM with fused bias+relu ----
  {
    ISeg sa = {x_a, wa_hi, wa_lo, ha0, lin_a_b, NA, FA, NAp / 64};
    ISeg sb = {x_b, wb_hi, wb_lo, hb0, lin_b_b, NB, FB, NBp / 64};
    gemm_mfma_in<<<NAp / 64 + NBp / 64, 256, 0, stream>>>(sa, sb);
  }

  // ---- two GAT layers: logits -> edge softmax+agg (split-bf16 z) -> 8-wave MFMA GEMM ----
  auto run_layer = [&](int L, const float* haP, const float* hbP,
                       float* haN, float* hbN, const float* b_ab, const float* b_ba,
                       int relu) {
    compute_al4<<<((2 * (NA + NB)) * HEADS + 255) / 256, 256, 0, stream>>>(
        haP, hbP, vv + (size_t)L * 4 * HID * HEADS,
        als_ab, ald_ab, als_ba, ald_ba, NA, NB);
    GDir dab = {indptr_ab, srcs_ab, als_ab, ald_ab, haP, zab_hi, zab_lo};
    GDir dba = {indptr_ba, srcs_ba, als_ba, ald_ba, hbP, zba_hi, zba_lo};
    const int gab = 2 * L, gba = 2 * L + 1;
    MSeg mab = {zab_hi, zab_lo, WT + (size_t)gab * 131072, WT + (size_t)(4 + gab) * 131072,
                hbN, b_ab, NB, NBp / 64};
    MSeg mba = {zba_hi, zba_lo, WT + (size_t)gba * 131072, WT + (size_t)(4 + gba) * 131072,
                haN, b_ba, NA, NAp / 64};
    if (dual) {
      gat_edge2<<<(NB + NA + 3) / 4, 256, 0, stream>>>(dab, dba, NB, NB + NA);
      gemm_mfma8<<<NBp / 64 + NAp / 64, 512, 0, stream>>>(mab, mba, 1.f / HEADS, relu);
    } else {
      MSeg mz = {nullptr, nullptr, nullptr, nullptr, nullptr, nullptr, 0, 0};
      gat_edge2<<<(NB + 3) / 4, 256, 0, stream>>>(dab, dab, NB, NB);
      gemm_mfma8<<<NBp / 64, 512, 0, stream>>>(mab, mz, 1.f / HEADS, relu);
      gat_edge2<<<(NA + 3) / 4, 256, 0, stream>>>(dba, dba, NA, NA);
      gemm_mfma8<<<NAp / 64, 512, 0, stream>>>(mba, mz, 1.f / HEADS, relu);
    }
  };

  run_layer(0, ha0, hb0, ha1, hb1, (const float*)d_in[16], (const float*)d_in[21], 1);
  run_layer(1, ha1, hb1, ha2, hb2, (const float*)d_in[26], (const float*)d_in[31], 0);

  // ---- fused pooled mean + FC ----
  pool_fin<<<320, 256, 0, stream>>>(ha2, hb2, batch_a, batch_b, fc_w, fc_b,
                                    gsum, ticket, (float*)d_out, NA, NB, NG);
}

// Round 10
// 370.424 us; speedup vs baseline: 1.1701x; 1.0040x over previous
//
#include <hip/hip_runtime.h>
#include <math.h>

#define HID 128
#define HEADS 8

typedef __attribute__((ext_vector_type(8))) short s16x8;
typedef __attribute__((ext_vector_type(4))) float f32x4;

__device__ __forceinline__ unsigned short bf16_rne(float x) {
  unsigned u = __float_as_uint(x);
  unsigned r = u + 0x7FFFu + ((u >> 16) & 1u);
  return (unsigned short)(r >> 16);
}
__device__ __forceinline__ float bf16f(unsigned short h) {
  return __uint_as_float(((unsigned)h) << 16);
}

// ====== fused prep: transposed bf16-split layer-W + make_v + input-W split + histogram ======
struct PrepArgs {
  const float* W[8];
  const float* a[8];
  unsigned short* WThi[4];
  unsigned short* WTlo[4];
  float* v[8];
};
struct PrepX {
  const float* lwa; const float* lwb;
  unsigned short *wa_hi, *wa_lo, *wb_hi, *wb_lo;
  int KA, KB, nwa, nwb;
};

__global__ __launch_bounds__(256) void prep_hist(
    PrepArgs p, PrepX px,
    const int* __restrict__ dst_ab, const int* __restrict__ dst_ba,
    int* __restrict__ cnt_ab, int* __restrict__ cnt_ba, int E)
{
  int bid = blockIdx.x;
  if (bid < 2048) {  // WT[g][c*1024 + (h*128+k)] = split(Ws[g][k*1024 + h*128 + c])
    int g = bid >> 9;
    int idx = ((bid & 511) << 8) + threadIdx.x;
    int kidx = idx & 1023;
    int c = idx >> 10;
    int h = kidx >> 7, k = kidx & 127;
    float wv = p.W[2 * g][(size_t)k * (HEADS * HID) + h * HID + c];
    unsigned short hi = bf16_rne(wv);
    unsigned short lo = bf16_rne(wv - bf16f(hi));
    p.WThi[g][idx] = hi;
    p.WTlo[g][idx] = lo;
  } else if (bid < 2080) {  // v[wi][k*8+h] = sum_c W[wi][k, h*128+c] * a[wi][h,c]
    int u = bid - 2048;
    int wi = u >> 2;
    int gid = ((u & 3) << 8) + threadIdx.x;
    int k = gid >> 3, h = gid & 7;
    const float* wr = p.W[wi] + (size_t)k * (HEADS * HID) + h * HID;
    const float* ar = p.a[wi] + (size_t)h * HID;
    float s = 0.f;
    for (int c = 0; c < HID; c++) s = fmaf(wr[c], ar[c], s);
    p.v[wi][gid] = s;
  } else if (bid < 2080 + px.nwa) {  // wa[c*KA + k] = split(lwa[k*HID + c])
    int idx = (bid - 2080) * 256 + threadIdx.x;
    if (idx < px.KA * HID) {
      int k = idx % px.KA, c = idx / px.KA;
      float wv = px.lwa[(size_t)k * HID + c];
      unsigned short hi = bf16_rne(wv);
      unsigned short lo = bf16_rne(wv - bf16f(hi));
      px.wa_hi[idx] = hi;
      px.wa_lo[idx] = lo;
    }
  } else if (bid < 2080 + px.nwa + px.nwb) {
    int idx = (bid - 2080 - px.nwa) * 256 + threadIdx.x;
    if (idx < px.KB * HID) {
      int k = idx % px.KB, c = idx / px.KB;
      float wv = px.lwb[(size_t)k * HID + c];
      unsigned short hi = bf16_rne(wv);
      unsigned short lo = bf16_rne(wv - bf16f(hi));
      px.wb_hi[idx] = hi;
      px.wb_lo[idx] = lo;
    }
  } else {                  // degree histogram, both directions
    int gid = (bid - 2080 - px.nwa - px.nwb) * 256 + threadIdx.x;
    if (gid < E) atomicAdd(&cnt_ab[dst_ab[gid]], 1);
    else if (gid < 2 * E) atomicAdd(&cnt_ba[dst_ba[gid - E]], 1);
  }
}

__global__ __launch_bounds__(1024) void scan2(
    const int* __restrict__ cnt_ab, const int* __restrict__ cnt_ba,
    int* __restrict__ ip_ab, int* __restrict__ ip_ba, int n_ab, int n_ba)
{
  const int* cnt = (blockIdx.x == 0) ? cnt_ab : cnt_ba;
  int* indptr = (blockIdx.x == 0) ? ip_ab : ip_ba;
  int n = (blockIdx.x == 0) ? n_ab : n_ba;
  __shared__ int parts[1024];
  const int tid = threadIdx.x;
  const int base = tid * 10;
  int local[10];
  int s = 0;
#pragma unroll
  for (int j = 0; j < 10; j++) {
    int v = (base + j < n) ? cnt[base + j] : 0;
    local[j] = v; s += v;
  }
  parts[tid] = s;
  __syncthreads();
  for (int off = 1; off < 1024; off <<= 1) {
    int v = (tid >= off) ? parts[tid - off] : 0;
    __syncthreads();
    parts[tid] += v;
    __syncthreads();
  }
  int ex = parts[tid] - s;
#pragma unroll
  for (int j = 0; j < 10; j++) {
    if (base + j < n) indptr[base + j] = ex;
    ex += local[j];
  }
  if (tid == 1023) indptr[n] = parts[1023];
}

__global__ __launch_bounds__(256) void scatter2(
    const int* __restrict__ edge_ab, const int* __restrict__ edge_ba,
    const int* __restrict__ ip_ab, const int* __restrict__ ip_ba,
    int* __restrict__ cur_ab, int* __restrict__ cur_ba,
    int* __restrict__ srcs_ab, int* __restrict__ srcs_ba, int E)
{
  int gid = blockIdx.x * 256 + threadIdx.x;
  if (gid < E) {
    int d = edge_ab[E + gid];
    int pos = ip_ab[d] + atomicAdd(&cur_ab[d], 1);
    srcs_ab[pos] = edge_ab[gid];
  } else if (gid < 2 * E) {
    int g = gid - E;
    int d = edge_ba[E + g];
    int pos = ip_ba[d] + atomicAdd(&cur_ba[d], 1);
    srcs_ba[pos] = edge_ba[g];
  }
}

// ===== input linears: MFMA bf16-split GEMM, fp32 A split on the fly, fused bias+relu =======
struct ISeg {
  const float* A;
  const unsigned short* Bhi; const unsigned short* Blo;
  float* out; const float* bias; int M; int K; int yb;
};

__global__ __launch_bounds__(256) void gemm_mfma_in(ISeg s0, ISeg s1)
{
  __shared__ __align__(16) unsigned short smem[12288];  // Ahi[64][32] Alo Bhi[128][32] Blo
  const int tid = threadIdx.x;
  const float* A; const unsigned short *Bhi, *Blo; const float* bias; float* out;
  int M, K, ytile;
  if ((int)blockIdx.x < s0.yb) {
    A = s0.A; Bhi = s0.Bhi; Blo = s0.Blo; out = s0.out; bias = s0.bias;
    M = s0.M; K = s0.K; ytile = blockIdx.x;
  } else {
    A = s1.A; Bhi = s1.Bhi; Blo = s1.Blo; out = s1.out; bias = s1.bias;
    M = s1.M; K = s1.K; ytile = blockIdx.x - s0.yb;
  }
  const int bm = ytile * 64;
  const int nks = K >> 5;

  const int sr = tid >> 2;
  const int sg = tid & 3;
  const int g1 = sg ^ ((sr >> 1) & 3);
  const int sr2 = sr + 64;
  const int g2 = sg ^ ((sr2 >> 1) & 3);
  const int aslot  = sr * 32 + g1 * 8;
  const int bslotA = sr * 32 + g1 * 8;
  const int bslotB = sr2 * 32 + g2 * 8;
  const int gr = bm + sr;
  const bool arow_ok = (gr < M);
  const float* gA = A + (size_t)gr * K + sg * 8;
  const unsigned short* gB0 = Bhi + (size_t)sr  * K + sg * 8;
  const unsigned short* gB1 = Bhi + (size_t)sr2 * K + sg * 8;
  const unsigned short* gC0 = Blo + (size_t)sr  * K + sg * 8;
  const unsigned short* gC1 = Blo + (size_t)sr2 * K + sg * 8;

  const int l = tid & 63;
  const int w = tid >> 6;
  const int kg = l >> 4;
  int aoff[4], boff[2];
#pragma unroll
  for (int mi = 0; mi < 4; mi++) {
    int r = mi * 16 + (l & 15);
    aoff[mi] = r * 32 + (kg ^ ((r >> 1) & 3)) * 8;
  }
#pragma unroll
  for (int ni = 0; ni < 2; ni++) {
    int r = w * 32 + ni * 16 + (l & 15);
    boff[ni] = r * 32 + (kg ^ ((r >> 1) & 3)) * 8;
  }

  f32x4 acc[4][2];
  const f32x4 z4 = {0.f, 0.f, 0.f, 0.f};
#pragma unroll
  for (int mi = 0; mi < 4; mi++)
#pragma unroll
    for (int ni = 0; ni < 2; ni++) acc[mi][ni] = z4;

  float4 fa0 = make_float4(0.f, 0.f, 0.f, 0.f), fa1 = fa0;
  if (arow_ok) { fa0 = *(const float4*)gA; fa1 = *(const float4*)(gA + 4); }
  uint4 rB0 = *(const uint4*)gB0;
  uint4 rB1 = *(const uint4*)gB1;
  uint4 rC0 = *(const uint4*)gC0;
  uint4 rC1 = *(const uint4*)gC1;

  for (int ks = 0; ks < nks; ks++) {
    {
      const float f[8] = {fa0.x, fa0.y, fa0.z, fa0.w, fa1.x, fa1.y, fa1.z, fa1.w};
      unsigned au[4], lu[4];
#pragma unroll
      for (int i = 0; i < 4; i++) {
        unsigned short h0 = bf16_rne(f[2 * i]);
        unsigned short l0 = bf16_rne(f[2 * i] - bf16f(h0));
        unsigned short h1 = bf16_rne(f[2 * i + 1]);
        unsigned short l1 = bf16_rne(f[2 * i + 1] - bf16f(h1));
        au[i] = (unsigned)h0 | ((unsigned)h1 << 16);
        lu[i] = (unsigned)l0 | ((unsigned)l1 << 16);
      }
      *(uint4*)&smem[aslot]        = make_uint4(au[0], au[1], au[2], au[3]);
      *(uint4*)&smem[2048 + aslot] = make_uint4(lu[0], lu[1], lu[2], lu[3]);
    }
    *(uint4*)&smem[4096 + bslotA] = rB0;
    *(uint4*)&smem[4096 + bslotB] = rB1;
    *(uint4*)&smem[8192 + bslotA] = rC0;
    *(uint4*)&smem[8192 + bslotB] = rC1;
    __syncthreads();
    if (ks < nks - 1) {
      const int k0 = (ks + 1) * 32;
      if (arow_ok) {
        fa0 = *(const float4*)(gA + k0);
        fa1 = *(const float4*)(gA + k0 + 4);
      }
      rB0 = *(const uint4*)(gB0 + k0);
      rB1 = *(const uint4*)(gB1 + k0);
      rC0 = *(const uint4*)(gC0 + k0);
      rC1 = *(const uint4*)(gC1 + k0);
    }
    s16x8 bh0 = *(const s16x8*)&smem[4096 + boff[0]];
    s16x8 bh1 = *(const s16x8*)&smem[4096 + boff[1]];
    s16x8 bl0 = *(const s16x8*)&smem[8192 + boff[0]];
    s16x8 bl1 = *(const s16x8*)&smem[8192 + boff[1]];
#pragma unroll
    for (int mi = 0; mi < 4; mi++) {
      s16x8 ah = *(const s16x8*)&smem[aoff[mi]];
      s16x8 al = *(const s16x8*)&smem[2048 + aoff[mi]];
      acc[mi][0] = __builtin_amdgcn_mfma_f32_16x16x32_bf16(ah, bh0, acc[mi][0], 0, 0, 0);
      acc[mi][1] = __builtin_amdgcn_mfma_f32_16x16x32_bf16(ah, bh1, acc[mi][1], 0, 0, 0);
      acc[mi][0] = __builtin_amdgcn_mfma_f32_16x16x32_bf16(ah, bl0, acc[mi][0], 0, 0, 0);
      acc[mi][1] = __builtin_amdgcn_mfma_f32_16x16x32_bf16(ah, bl1, acc[mi][1], 0, 0, 0);
      acc[mi][0] = __builtin_amdgcn_mfma_f32_16x16x32_bf16(al, bh0, acc[mi][0], 0, 0, 0);
      acc[mi][1] = __builtin_amdgcn_mfma_f32_16x16x32_bf16(al, bh1, acc[mi][1], 0, 0, 0);
      acc[mi][0] = __builtin_amdgcn_mfma_f32_16x16x32_bf16(al, bl0, acc[mi][0], 0, 0, 0);
      acc[mi][1] = __builtin_amdgcn_mfma_f32_16x16x32_bf16(al, bl1, acc[mi][1], 0, 0, 0);
    }
    __syncthreads();
  }

  const int q = l >> 4, cl = l & 15;
#pragma unroll
  for (int ni = 0; ni < 2; ni++) {
    const int col = w * 32 + ni * 16 + cl;
    const float bv = bias[col];
#pragma unroll
    for (int mi = 0; mi < 4; mi++) {
      const int r0 = bm + mi * 16 + q * 4;
      const f32x4 v = acc[mi][ni];
#pragma unroll
      for (int j = 0; j < 4; j++) {
        const int r = r0 + j;
        if (r < M) {
          float x = v[j] + bv;
          x = fmaxf(x, 0.f);
          out[(size_t)r * HID + col] = x;
        }
      }
    }
  }
}

// ================= 4 attention-logit arrays per layer in one launch =================
__global__ __launch_bounds__(256) void compute_al4(
    const float* __restrict__ ha, const float* __restrict__ hb,
    const float* __restrict__ v4,
    float* __restrict__ o0, float* __restrict__ o1,
    float* __restrict__ o2, float* __restrict__ o3, int na, int nb)
{
  __shared__ float vsh[4 * HID * HEADS];
  for (int i = threadIdx.x; i < 4 * HID * HEADS; i += 256) vsh[i] = v4[i];
  __syncthreads();
  int gid = blockIdx.x * 256 + threadIdx.x;
  int row = gid >> 3, h = gid & 7;
  const float* hr; float* o; int q, rl;
  if (row < na)                    { q = 0; rl = row;               hr = ha; o = o0; }
  else if (row < na + nb)          { q = 1; rl = row - na;          hr = hb; o = o1; }
  else if (row < na + 2 * nb)      { q = 2; rl = row - na - nb;     hr = hb; o = o2; }
  else if (row < 2 * na + 2 * nb)  { q = 3; rl = row - na - 2 * nb; hr = ha; o = o3; }
  else return;
  hr += (size_t)rl * HID;
  const float* vq = vsh + q * HID * HEADS;
  float s = 0.f;
  for (int k = 0; k < HID; k++) s = fmaf(hr[k], vq[k * HEADS + h], s);
  o[(size_t)rl * HEADS + h] = s;
}

// ================= wave-per-node segment softmax + aggregation; writes bf16-split z =========
// ROUND-5 PROVEN CONFIG (60 VGPR, batch-4 gathers, merged logit+exp pass, no launch bound).
struct GDir {
  const int* indptr; const int* srcs;
  const float* als; const float* ald;
  const float* h;
  unsigned short* zhi; unsigned short* zlo;
};

__global__ __launch_bounds__(256) void gat_edge2(GDir d0, GDir d1, int n0, int ntot)
{
  const int w = threadIdx.x >> 6;
  const int lane = threadIdx.x & 63;
  const int g = blockIdx.x * 4 + w;
  if (g >= ntot) return;
  const bool first = (g < n0);
  const int n = first ? g : g - n0;
  const int* indptr = first ? d0.indptr : d1.indptr;
  const int* srcs   = first ? d0.srcs   : d1.srcs;
  const float* als  = first ? d0.als    : d1.als;
  const float* ald  = first ? d0.ald    : d1.ald;
  const float* hsrc = first ? d0.h      : d1.h;
  unsigned short* zh = (first ? d0.zhi : d1.zhi) + (size_t)n * (HEADS * HID);
  unsigned short* zl = (first ? d0.zlo : d1.zlo) + (size_t)n * (HEADS * HID);

  const int base = indptr[n];
  const int deg = indptr[n + 1] - base;
  if (deg == 0) {
#pragma unroll
    for (int hh = 0; hh < HEADS; hh++) {
      *(unsigned*)(zh + hh * HID + 2 * lane) = 0u;
      *(unsigned*)(zl + hh * HID + 2 * lane) = 0u;
    }
    return;
  }
  const int eh = lane >> 3, h = lane & 7;
  const float aldn = ald[(size_t)n * HEADS + h];
  const int nch = (deg + 7) >> 3;
  const int ncc = nch < 4 ? nch : 4;

  // pass A: batched srcs loads + als gathers, exp (no max shift), denom
  int sc[4];
  float vc[4];
#pragma unroll
  for (int c = 0; c < 4; c++) {
    int e = c * 8 + eh;
    sc[c] = (c < ncc && e < deg) ? srcs[base + e] : -1;
  }
#pragma unroll
  for (int c = 0; c < 4; c++)
    vc[c] = (sc[c] >= 0) ? als[(size_t)sc[c] * HEADS + h] : 0.f;
  float den = 0.f;
#pragma unroll
  for (int c = 0; c < 4; c++) {
    float v = vc[c] + aldn;
    v = v > 0.f ? v : 0.2f * v;
    float ex = (sc[c] >= 0) ? expf(v) : 0.f;
    vc[c] = ex;
    den += ex;
  }
  for (int e0 = 32; e0 < deg; e0 += 8) {   // statistically-empty tail (deg>32)
    int e = e0 + eh;
    if (e < deg) {
      int s = srcs[base + e];
      float v = als[(size_t)s * HEADS + h] + aldn;
      v = v > 0.f ? v : 0.2f * v;
      den += expf(v);
    }
  }
  den += __shfl_xor(den, 8);
  den += __shfl_xor(den, 16);
  den += __shfl_xor(den, 32);

  // pass B: per 8-edge chunk, two half-batches of 4 concurrent row gathers
  float acc[16];
#pragma unroll
  for (int i = 0; i < 16; i++) acc[i] = 0.f;
#pragma unroll
  for (int c = 0; c < 4; c++) {
    if (c >= ncc) break;
    const int rem = deg - c * 8;
    const int elim = rem < 8 ? rem : 8;
#pragma unroll
    for (int half = 0; half < 2; half++) {
      if (half * 4 >= elim) break;
      int sj[4];
#pragma unroll
      for (int j = 0; j < 4; j++) {
        int s = __shfl(sc[c], (half * 4 + j) * 8);
        sj[j] = s < 0 ? 0 : s;
      }
      float2 hv[4];
#pragma unroll
      for (int j = 0; j < 4; j++)
        hv[j] = *(const float2*)(hsrc + (size_t)sj[j] * HID + 2 * lane);
#pragma unroll
      for (int j = 0; j < 4; j++) {
#pragma unroll
        for (int hh = 0; hh < 8; hh++) {
          float a = __shfl(vc[c], (half * 4 + j) * 8 + hh);
          acc[2 * hh]     = fmaf(a, hv[j].x, acc[2 * hh]);
          acc[2 * hh + 1] = fmaf(a, hv[j].y, acc[2 * hh + 1]);
        }
      }
    }
  }
  for (int e0 = 32; e0 < deg; e0 += 8) {   // statistically-empty tail: recompute exps
    int e = e0 + eh;
    int s = (e < deg) ? srcs[base + e] : -1;
    float ex = 0.f;
    if (s >= 0) {
      float v = als[(size_t)s * HEADS + h] + aldn;
      v = v > 0.f ? v : 0.2f * v;
      ex = expf(v);
    }
    int elim = deg - e0; if (elim > 8) elim = 8;
    for (int e8 = 0; e8 < elim; e8++) {
      int ss = __shfl(s, e8 * 8);
      const float2 hvt = *(const float2*)(hsrc + (size_t)ss * HID + 2 * lane);
#pragma unroll
      for (int hh = 0; hh < 8; hh++) {
        float a = __shfl(ex, e8 * 8 + hh);
        acc[2 * hh]     = fmaf(a, hvt.x, acc[2 * hh]);
        acc[2 * hh + 1] = fmaf(a, hvt.y, acc[2 * hh + 1]);
      }
    }
  }
  // epilogue: fold 1/(den+eps), write split-bf16 z
#pragma unroll
  for (int hh = 0; hh < 8; hh++) {
    float dh = __shfl(den, hh);
    float inv = 1.f / (dh + 1e-16f);
    float x0 = acc[2 * hh] * inv;
    float x1 = acc[2 * hh + 1] * inv;
    unsigned short h0 = bf16_rne(x0), h1 = bf16_rne(x1);
    unsigned short l0 = bf16_rne(x0 - bf16f(h0)), l1 = bf16_rne(x1 - bf16f(h1));
    *(unsigned*)(zh + hh * HID + 2 * lane) = (unsigned)h0 | ((unsigned)h1 << 16);
    *(unsigned*)(zl + hh * HID + 2 * lane) = (unsigned)l0 | ((unsigned)l1 << 16);
  }
}

// ================= MFMA bf16x4-split GEMM, GRID SPLIT-K: [M x 1024] @ [1024 x 128] -> P =====
// BM=64, BN=128, BK=32; grid = (tiles, KS). R6/R9 A/B: grid split-K (1256 blocks, 8 K-steps)
// beats in-block 8-wave split (314 blocks, 43us) — parallelism is grid-shaped here.
struct MSeg {
  const unsigned short* Ahi; const unsigned short* Alo;
  const unsigned short* Bhi; const unsigned short* Blo;
  int M; int yb;
};

__global__ __launch_bounds__(256, 2) void gemm_mfma_splitk(
    MSeg s0, MSeg s1, float* __restrict__ P, int Mtot, int KS)
{
  __shared__ __align__(16) unsigned short smem[12288];  // Ahi[64][32] Alo Bhi[128][32] Blo
  const int tid = threadIdx.x;
  const unsigned short *Ahi, *Alo, *Bhi, *Blo; int M, ytile, rowbase;
  if ((int)blockIdx.x < s0.yb) {
    Ahi = s0.Ahi; Alo = s0.Alo; Bhi = s0.Bhi; Blo = s0.Blo;
    M = s0.M; ytile = blockIdx.x; rowbase = 0;
  } else {
    Ahi = s1.Ahi; Alo = s1.Alo; Bhi = s1.Bhi; Blo = s1.Blo;
    M = s1.M; ytile = blockIdx.x - s0.yb; rowbase = s0.yb * 64;
  }
  const int bm = ytile * 64;
  const int kchunk = 1024 / KS;
  const int kbeg = blockIdx.y * kchunk;
  const int nks = kchunk / 32;

  const int sr = tid >> 2;
  const int sg = tid & 3;
  const int g1 = sg ^ ((sr >> 1) & 3);
  const int sr2 = sr + 64;
  const int g2 = sg ^ ((sr2 >> 1) & 3);
  const int aslot  = sr * 32 + g1 * 8;
  const int bslotA = sr * 32 + g1 * 8;
  const int bslotB = sr2 * 32 + g2 * 8;
  const unsigned short* gA  = Ahi + (size_t)(bm + sr) * 1024 + kbeg + sg * 8;
  const unsigned short* gAl = Alo + (size_t)(bm + sr) * 1024 + kbeg + sg * 8;
  const unsigned short* gB0 = Bhi + (size_t)sr  * 1024 + kbeg + sg * 8;
  const unsigned short* gB1 = Bhi + (size_t)sr2 * 1024 + kbeg + sg * 8;
  const unsigned short* gC0 = Blo + (size_t)sr  * 1024 + kbeg + sg * 8;
  const unsigned short* gC1 = Blo + (size_t)sr2 * 1024 + kbeg + sg * 8;

  const int l = tid & 63;
  const int w = tid >> 6;
  const int kg = l >> 4;
  int aoff[4], boff[2];
#pragma unroll
  for (int mi = 0; mi < 4; mi++) {
    int r = mi * 16 + (l & 15);
    aoff[mi] = r * 32 + (kg ^ ((r >> 1) & 3)) * 8;
  }
#pragma unroll
  for (int ni = 0; ni < 2; ni++) {
    int r = w * 32 + ni * 16 + (l & 15);
    boff[ni] = r * 32 + (kg ^ ((r >> 1) & 3)) * 8;
  }

  f32x4 acc[4][2];
  const f32x4 z4 = {0.f, 0.f, 0.f, 0.f};
#pragma unroll
  for (int mi = 0; mi < 4; mi++)
#pragma unroll
    for (int ni = 0; ni < 2; ni++) acc[mi][ni] = z4;

  uint4 rA  = *(const uint4*)gA;
  uint4 rAl = *(const uint4*)gAl;
  uint4 rB0 = *(const uint4*)gB0;
  uint4 rB1 = *(const uint4*)gB1;
  uint4 rC0 = *(const uint4*)gC0;
  uint4 rC1 = *(const uint4*)gC1;

  for (int ks = 0; ks < nks; ks++) {
    *(uint4*)&smem[aslot]         = rA;
    *(uint4*)&smem[2048 + aslot]  = rAl;
    *(uint4*)&smem[4096 + bslotA] = rB0;
    *(uint4*)&smem[4096 + bslotB] = rB1;
    *(uint4*)&smem[8192 + bslotA] = rC0;
    *(uint4*)&smem[8192 + bslotB] = rC1;
    __syncthreads();
    if (ks < nks - 1) {
      const int k0 = (ks + 1) * 32;
      rA  = *(const uint4*)(gA  + k0);
      rAl = *(const uint4*)(gAl + k0);
      rB0 = *(const uint4*)(gB0 + k0);
      rB1 = *(const uint4*)(gB1 + k0);
      rC0 = *(const uint4*)(gC0 + k0);
      rC1 = *(const uint4*)(gC1 + k0);
    }
    s16x8 bh0 = *(const s16x8*)&smem[4096 + boff[0]];
    s16x8 bh1 = *(const s16x8*)&smem[4096 + boff[1]];
    s16x8 bl0 = *(const s16x8*)&smem[8192 + boff[0]];
    s16x8 bl1 = *(const s16x8*)&smem[8192 + boff[1]];
#pragma unroll
    for (int mi = 0; mi < 4; mi++) {
      s16x8 ah = *(const s16x8*)&smem[aoff[mi]];
      s16x8 al = *(const s16x8*)&smem[2048 + aoff[mi]];
      acc[mi][0] = __builtin_amdgcn_mfma_f32_16x16x32_bf16(ah, bh0, acc[mi][0], 0, 0, 0);
      acc[mi][1] = __builtin_amdgcn_mfma_f32_16x16x32_bf16(ah, bh1, acc[mi][1], 0, 0, 0);
      acc[mi][0] = __builtin_amdgcn_mfma_f32_16x16x32_bf16(ah, bl0, acc[mi][0], 0, 0, 0);
      acc[mi][1] = __builtin_amdgcn_mfma_f32_16x16x32_bf16(ah, bl1, acc[mi][1], 0, 0, 0);
      acc[mi][0] = __builtin_amdgcn_mfma_f32_16x16x32_bf16(al, bh0, acc[mi][0], 0, 0, 0);
      acc[mi][1] = __builtin_amdgcn_mfma_f32_16x16x32_bf16(al, bh1, acc[mi][1], 0, 0, 0);
      acc[mi][0] = __builtin_amdgcn_mfma_f32_16x16x32_bf16(al, bl0, acc[mi][0], 0, 0, 0);
      acc[mi][1] = __builtin_amdgcn_mfma_f32_16x16x32_bf16(al, bl1, acc[mi][1], 0, 0, 0);
    }
    __syncthreads();
  }

  // write fp32 partials to P slice (C/D: col=l&15, row=(l>>4)*4+j)
  const int q = l >> 4, cl = l & 15;
  const size_t prow0 = (size_t)blockIdx.y * Mtot + rowbase + bm;
#pragma unroll
  for (int ni = 0; ni < 2; ni++) {
    const int col = w * 32 + ni * 16 + cl;
#pragma unroll
    for (int mi = 0; mi < 4; mi++) {
      const int r0 = mi * 16 + q * 4;
      const f32x4 v = acc[mi][ni];
#pragma unroll
      for (int j = 0; j < 4; j++) {
        const int r = r0 + j;
        if (bm + r < M) P[(prow0 + r) * HID + col] = v[j];
      }
    }
  }
}

// ================= reduce KS partials + scale + bias + act =================
struct RSeg { float* out; const float* bias; int M; int rowbase; };

__global__ __launch_bounds__(256) void reduce_epi(
    const float* __restrict__ P, int Mtot, int KS, float scale, int do_relu,
    RSeg s0, RSeg s1)
{
  int idx = blockIdx.x * 256 + threadIdx.x;
  if (idx >= Mtot * 32) return;
  int r = idx >> 5;
  int c = (idx & 31) << 2;
  float* outp; const float* bias; int rl;
  if (s1.M > 0 && r >= s1.rowbase) {
    rl = r - s1.rowbase; if (rl >= s1.M) return; outp = s1.out; bias = s1.bias;
  } else {
    rl = r; if (rl >= s0.M) return; outp = s0.out; bias = s0.bias;
  }
  float4 acc = make_float4(0.f, 0.f, 0.f, 0.f);
  for (int z = 0; z < KS; z++) {
    const float4 v = *(const float4*)(P + ((size_t)z * Mtot + r) * HID + c);
    acc.x += v.x; acc.y += v.y; acc.z += v.z; acc.w += v.w;
  }
  const float4 b = *(const float4*)(bias + c);
  acc.x = acc.x * scale + b.x;
  acc.y = acc.y * scale + b.y;
  acc.z = acc.z * scale + b.z;
  acc.w = acc.w * scale + b.w;
  if (do_relu) {
    acc.x = acc.x > 0.f ? acc.x : 0.f;
    acc.y = acc.y > 0.f ? acc.y : 0.f;
    acc.z = acc.z > 0.f ? acc.z : 0.f;
    acc.w = acc.w > 0.f ? acc.w : 0.f;
  }
  *(float4*)(outp + (size_t)rl * HID + c) = acc;
}

// ================= fused pool + FC (atomic-ticket last-block finalize) =================
__global__ __launch_bounds__(256) void pool_fin(
    const float* __restrict__ ha, const float* __restrict__ hb,
    const int* __restrict__ batch_a, const int* __restrict__ batch_b,
    const float* __restrict__ fc_w, const float* __restrict__ fc_b,
    float* __restrict__ gsum, int* __restrict__ ticket,
    float* __restrict__ out, int na, int nb, int ng)
{
  const bool isA = blockIdx.x < 160;
  const float* h = isA ? ha : hb;
  const int* batch = isA ? batch_a : batch_b;
  const float* wseg = isA ? fc_w : fc_w + HID;
  float* gs = isA ? gsum : gsum + 8;
  const int n = isA ? na : nb;
  const int b = isA ? blockIdx.x : blockIdx.x - 160;

  __shared__ float sg[8];
  __shared__ int lastf;
  if (threadIdx.x < 8) sg[threadIdx.x] = 0.f;
  __syncthreads();
  const int lane = threadIdx.x & 63;
  const int wv = threadIdx.x >> 6;
  const int gw = b * 4 + wv;
  const int tw = 160 * 4;
  const float2 w2 = *(const float2*)(wseg + lane * 2);
  for (int r = gw; r < n; r += tw) {
    float2 hv = *(const float2*)(h + (size_t)r * HID + lane * 2);
    float s = hv.x * w2.x + hv.y * w2.y;
#pragma unroll
    for (int off = 32; off > 0; off >>= 1) s += __shfl_down(s, off, 64);
    if (lane == 0) atomicAdd(&sg[batch[r]], s);
  }
  __syncthreads();
  if (threadIdx.x < 8) atomicAdd(&gs[threadIdx.x], sg[threadIdx.x]);
  if (threadIdx.x == 0) {
    __threadfence();
    int tk = atomicAdd(ticket, 1);
    lastf = (tk == (int)gridDim.x - 1);
  }
  __syncthreads();
  if (lastf) {
    int g = threadIdx.x;
    if (g < ng) {
      int l, r, lo;
      l = 0; r = na; while (l < r) { int m = (l + r) >> 1; if (batch_a[m] < g) l = m + 1; else r = m; } lo = l;
      r = na; while (l < r) { int m = (l + r) >> 1; if (batch_a[m] < g + 1) l = m + 1; else r = m; }
      int ca = l - lo; if (ca < 1) ca = 1;
      l = 0; r = nb; while (l < r) { int m = (l + r) >> 1; if (batch_b[m] < g) l = m + 1; else r = m; } lo = l;
      r = nb; while (l < r) { int m = (l + r) >> 1; if (batch_b[m] < g + 1) l = m + 1; else r = m; }
      int cb = l - lo; if (cb < 1) cb = 1;
      float va = atomicAdd(&gsum[g], 0.f);
      float vb = atomicAdd(&gsum[8 + g], 0.f);
      out[g] = va / (float)ca + vb / (float)cb + fc_b[0];
    }
  }
}

extern "C" void kernel_launch(void* const* d_in, const int* in_sizes, int n_in,
                              void* d_out, int out_size, void* d_ws, size_t ws_size,
                              hipStream_t stream)
{
  const float* x_a = (const float*)d_in[0];
  const float* x_b = (const float*)d_in[1];
  const int* edge_ab = (const int*)d_in[2];
  const int* edge_ba = (const int*)d_in[3];
  const int* batch_a = (const int*)d_in[4];
  const int* batch_b = (const int*)d_in[5];
  const float* lin_a_w = (const float*)d_in[6];
  const float* lin_a_b = (const float*)d_in[7];
  const float* lin_b_w = (const float*)d_in[8];
  const float* lin_b_b = (const float*)d_in[9];
  const float* fc_w = (const float*)d_in[10];
  const float* fc_b = (const float*)d_in[11];

  const int NA = in_sizes[4];
  const int NB = in_sizes[5];
  const int E  = in_sizes[2] / 2;
  const int FA = in_sizes[0] / NA;
  const int FB = in_sizes[1] / NB;
  const int NG = out_size;
  const int NMAX = NA > NB ? NA : NB;
  const int NAp = (NA + 127) & ~127, NBp = (NB + 127) & ~127;
  const int NMAXp = NAp > NBp ? NAp : NBp;
  const int Mtot = NAp + NBp;

  // ---- size model (mirrors carve order) ----
  auto al256 = [](size_t b) { return (b + 255) & ~(size_t)255; };
  size_t fixed = 0;
  fixed += 3 * al256((size_t)NAp * HID * 4) + 3 * al256((size_t)NBp * HID * 4);
  fixed += 2 * al256((size_t)NMAXp * 1024 * 2);                                   // z_ab hi+lo
  fixed += al256((size_t)8 * 131072 * 2);                                         // WT layer (4 x hi/lo)
  fixed += 2 * al256((size_t)FA * HID * 2) + 2 * al256((size_t)FB * HID * 2);     // WTin hi/lo
  fixed += al256((size_t)8 * HID * HEADS * 4);                                    // vv
  fixed += 2 * al256((size_t)NAp * HEADS * 4) + 2 * al256((size_t)NBp * HEADS * 4);
  fixed += al256(((size_t)4 * NMAX + 24) * 4);
  fixed += al256((size_t)(NB + 1) * 4) + al256((size_t)(NA + 1) * 4);
  fixed += 2 * al256((size_t)E * 4);
  fixed += 8192;
  const size_t zba_sz = 2 * al256((size_t)NAp * 1024 * 2);
  const size_t pslice = al256((size_t)Mtot * HID * 4);

  int KS = 4; bool dual = true;
  if (fixed + zba_sz + 4 * pslice <= ws_size)      { dual = true;  KS = 4; }
  else if (fixed + zba_sz + 2 * pslice <= ws_size) { dual = true;  KS = 2; }
  else if (fixed + 4 * pslice <= ws_size)          { dual = false; KS = 4; }
  else if (fixed + 2 * pslice <= ws_size)          { dual = false; KS = 2; }
  else if (fixed + 1 * pslice <= ws_size)          { dual = false; KS = 1; }
  else return;  // loud failure (out stays poisoned)

  char* w = (char*)d_ws;
  auto carve = [&](size_t bytes) -> void* {
    void* p = (void*)w;
    w += (bytes + 255) & ~(size_t)255;
    return p;
  };
  float* ha0 = (float*)carve((size_t)NAp * HID * 4);
  float* hb0 = (float*)carve((size_t)NBp * HID * 4);
  float* ha1 = (float*)carve((size_t)NAp * HID * 4);
  float* hb1 = (float*)carve((size_t)NBp * HID * 4);
  float* ha2 = (float*)carve((size_t)NAp * HID * 4);
  float* hb2 = (float*)carve((size_t)NBp * HID * 4);
  unsigned short* zab_hi = (unsigned short*)carve((size_t)NMAXp * 1024 * 2);
  unsigned short* zab_lo = (unsigned short*)carve((size_t)NMAXp * 1024 * 2);
  unsigned short* zba_hi = dual ? (unsigned short*)carve((size_t)NAp * 1024 * 2) : zab_hi;
  unsigned short* zba_lo = dual ? (unsigned short*)carve((size_t)NAp * 1024 * 2) : zab_lo;
  float* P = (float*)carve((size_t)KS * Mtot * HID * 4);
  unsigned short* WT = (unsigned short*)carve((size_t)8 * 131072 * 2);
  unsigned short* wa_hi = (unsigned short*)carve((size_t)FA * HID * 2);
  unsigned short* wa_lo = (unsigned short*)carve((size_t)FA * HID * 2);
  unsigned short* wb_hi = (unsigned short*)carve((size_t)FB * HID * 2);
  unsigned short* wb_lo = (unsigned short*)carve((size_t)FB * HID * 2);
  float* vv  = (float*)carve((size_t)8 * HID * HEADS * 4);
  float* als_ab = (float*)carve((size_t)NAp * HEADS * 4);
  float* ald_ab = (float*)carve((size_t)NBp * HEADS * 4);
  float* als_ba = (float*)carve((size_t)NBp * HEADS * 4);
  float* ald_ba = (float*)carve((size_t)NAp * HEADS * 4);
  int* csrblk = (int*)carve(((size_t)4 * NMAX + 24) * 4);
  int* indptr_ab = (int*)carve((size_t)(NB + 1) * 4);
  int* indptr_ba = (int*)carve((size_t)(NA + 1) * 4);
  int* srcs_ab   = (int*)carve((size_t)E * 4);
  int* srcs_ba   = (int*)carve((size_t)E * 4);
  if ((size_t)(w - (char*)d_ws) > ws_size) return;

  int* cnt_ab = csrblk;
  int* cnt_ba = csrblk + NMAX;
  int* cur_ab = csrblk + 2 * NMAX;
  int* cur_ba = csrblk + 3 * NMAX;
  float* gsum = (float*)(csrblk + 4 * NMAX);
  int* ticket = csrblk + 4 * NMAX + 16;

  hipMemsetAsync(csrblk, 0, ((size_t)4 * NMAX + 24) * 4, stream);

  // ---- fused weight prep (layer WT + v + input WT) + histogram ----
  PrepArgs pa;
  const int wi_idx[8] = {12, 13, 17, 18, 22, 23, 27, 28};
  const int ai_idx[8] = {14, 15, 19, 20, 24, 25, 29, 30};
  for (int i = 0; i < 8; i++) {
    pa.W[i] = (const float*)d_in[wi_idx[i]];
    pa.a[i] = (const float*)d_in[ai_idx[i]];
    pa.v[i] = vv + (size_t)i * HID * HEADS;
  }
  for (int g = 0; g < 4; g++) {
    pa.WThi[g] = WT + (size_t)g * 131072;
    pa.WTlo[g] = WT + (size_t)(4 + g) * 131072;
  }
  PrepX px;
  px.lwa = lin_a_w; px.lwb = lin_b_w;
  px.wa_hi = wa_hi; px.wa_lo = wa_lo; px.wb_hi = wb_hi; px.wb_lo = wb_lo;
  px.KA = FA; px.KB = FB;
  px.nwa = (FA * HID + 255) / 256;
  px.nwb = (FB * HID + 255) / 256;
  const int hist_b = (2 * E + 255) / 256;
  prep_hist<<<2080 + px.nwa + px.nwb + hist_b, 256, 0, stream>>>(
      pa, px, edge_ab + E, edge_ba + E, cnt_ab, cnt_ba, E);
  scan2<<<2, 1024, 0, stream>>>(cnt_ab, cnt_ba, indptr_ab, indptr_ba, NB, NA);
  scatter2<<<(2 * E + 255) / 256, 256, 0, stream>>>(
      edge_ab, edge_ba, indptr_ab, indptr_ba, cur_ab, cur_ba, srcs_ab, srcs_ba, E);

  // ---- input linears: MFMA split GEMM with fused bias+relu ----
  {
    ISeg sa = {x_a, wa_hi, wa_lo, ha0, lin_a_b, NA, FA, NAp / 64};
    ISeg sb = {x_b, wb_hi, wb_lo, hb0, lin_b_b, NB, FB, NBp / 64};
    gemm_mfma_in<<<NAp / 64 + NBp / 64, 256, 0, stream>>>(sa, sb);
  }

  const int red_grid = (Mtot * 32 + 255) / 256;
  const RSeg rnone = {nullptr, nullptr, 0, 0};

  // ---- two GAT layers: logits -> edge softmax+agg (split-bf16 z) -> grid split-K MFMA ----
  auto run_layer = [&](int L, const float* haP, const float* hbP,
                       float* haN, float* hbN, const float* b_ab, const float* b_ba,
                       int relu) {
    compute_al4<<<((2 * (NA + NB)) * HEADS + 255) / 256, 256, 0, stream>>>(
        haP, hbP, vv + (size_t)L * 4 * HID * HEADS,
        als_ab, ald_ab, als_ba, ald_ba, NA, NB);
    GDir dab = {indptr_ab, srcs_ab, als_ab, ald_ab, haP, zab_hi, zab_lo};
    GDir dba = {indptr_ba, srcs_ba, als_ba, ald_ba, hbP, zba_hi, zba_lo};
    const int gab = 2 * L, gba = 2 * L + 1;
    MSeg mab = {zab_hi, zab_lo, WT + (size_t)gab * 131072, WT + (size_t)(4 + gab) * 131072,
                NB, NBp / 64};
    MSeg mba = {zba_hi, zba_lo, WT + (size_t)gba * 131072, WT + (size_t)(4 + gba) * 131072,
                NA, NAp / 64};
    if (dual) {
      gat_edge2<<<(NB + NA + 3) / 4, 256, 0, stream>>>(dab, dba, NB, NB + NA);
      gemm_mfma_splitk<<<dim3(NBp / 64 + NAp / 64, KS), 256, 0, stream>>>(mab, mba, P, Mtot, KS);
      RSeg r0 = {hbN, b_ab, NB, 0};
      RSeg r1 = {haN, b_ba, NA, NBp};
      reduce_epi<<<red_grid, 256, 0, stream>>>(P, Mtot, KS, 1.f / HEADS, relu, r0, r1);
    } else {
      MSeg mz = {nullptr, nullptr, nullptr, nullptr, 0, 0};
      gat_edge2<<<(NB + 3) / 4, 256, 0, stream>>>(dab, dab, NB, NB);
      gemm_mfma_splitk<<<dim3(NBp / 64, KS), 256, 0, stream>>>(mab, mz, P, NBp, KS);
      RSeg r0 = {hbN, b_ab, NB, 0};
      reduce_epi<<<(NBp * 32 + 255) / 256, 256, 0, stream>>>(P, NBp, KS, 1.f / HEADS, relu, r0, rnone);
      gat_edge2<<<(NA + 3) / 4, 256, 0, stream>>>(dba, dba, NA, NA);
      gemm_mfma_splitk<<<dim3(NAp / 64, KS), 256, 0, stream>>>(mba, mz, P, NAp, KS);
      RSeg r1 = {haN, b_ba, NA, 0};
      reduce_epi<<<(NAp * 32 + 255) / 256, 256, 0, stream>>>(P, NAp, KS, 1.f / HEADS, relu, r1, rnone);
    }
  };

  run_layer(0, ha0, hb0, ha1, hb1, (const float*)d_in[16], (const float*)d_in[21], 1);
  run_layer(1, ha1, hb1, ha2, hb2, (const float*)d_in[26], (const float*)d_in[31], 0);

  // ---- fused pooled mean + FC ----
  pool_fin<<<320, 256, 0, stream>>>(ha2, hb2, batch_a, batch_b, fc_w, fc_b,
                                    gsum, ticket, (float*)d_out, NA, NB, NG);
}